// Round 5
// baseline (1183.978 us; speedup 1.0000x reference)
//
#include <hip/hip_runtime.h>
#include <hip/hip_bf16.h>
#include <hip/hip_fp16.h>

// GCN, bucket-sorted edge list + per-bucket LDS-accumulator aggregation.
//  - MEASURED MODEL (r1-r4): everything per-edge is LDS-ATOMIC-OP bound at
//    ~5.5us per M lane-ops (binscatter 32M=173.7us r4; bagg1 16M; bagg2 pairs
//    of kernels 32M; independent of occupancy/banking/gather traffic).
//    => optimize by DELETING counting passes, not by tuning memory.
//  - r5 restructure: count ONCE. k_count writes per-(bin,tile) counts to a
//    global matrix (8MB) + deg via GLOBAL atomics (different pipe, overlapped).
//    k_scanA/k_scanB turn the matrix into deterministic chunk bases ->
//    k_place pays ONLY the 16M placement atomics (no recount, no gcur).
//    binhist (16M ops) and prep's count (16M ops) are eliminated.
//  - 1024 bins = (dst>>B2) x (src < N/2): layer 2 runs lo/hi phase kernels,
//    each gathering from a 4MB L2-fit half of hfull; ds_pk_add_f16 packs
//    ch0/ch1 into one LDS atomic (r4: -90us validated).
//  - bucket segments padded to x4 edges with sentinel 0x80000000; agg loops
//    branchless (sentinel -> add 0 at index 0).

constexpr int NT = 256;
constexpr int SCAN_E = 1024;   // fallback scan tile
constexpr int B2 = 11;
constexpr int BN = 1 << B2;    // 2048 nodes / bucket
constexpr int NBMAX = 512;     // max dst buckets
constexpr int NBIN = 1024;     // dst-bucket x src-half bins
constexpr int TILE = 8192;     // edges per partition tile
constexpr int AT = 1024;       // threads for per-bucket agg kernels
constexpr int SENT = (int)0x80000000;

typedef int   v4i __attribute__((ext_vector_type(4)));
typedef float v2f __attribute__((ext_vector_type(2)));

__device__ __forceinline__ int4 ldnt4(const int* p) {
    v4i v = __builtin_nontemporal_load((const v4i*)p);
    int4 r; r.x = v.x; r.y = v.y; r.z = v.z; r.w = v.w; return r;
}
__device__ __forceinline__ float2 ldnt2f(const float* p) {
    v2f v = __builtin_nontemporal_load((const v2f*)p);
    return make_float2(v.x, v.y);
}
__device__ __forceinline__ float2 h2f2(unsigned u) {
    __half2 h = __builtin_bit_cast(__half2, u);
    return __half22float2(h);
}
__device__ __forceinline__ unsigned f2h2(float a, float b) {
    return __builtin_bit_cast(unsigned, __floats2half2_rn(a, b));
}
// native packed-half LDS atomic add (gfx950 ds_pk_add_f16), fire-and-forget.
// __syncthreads() drains lgkmcnt(0), guaranteeing completion before epilogue.
__device__ __forceinline__ void pk_add_lds(unsigned* p, unsigned v) {
    asm volatile("ds_pk_add_f16 %0, %1"
                 :: "v"((unsigned)(size_t)p), "v"(v) : "memory");
}

// ========== k_count: per-(bin,tile) counts -> matrix; deg via global atomics ==
__global__ void k_count(const int* __restrict__ src, const int* __restrict__ dst,
                        int* __restrict__ cntmat, int* __restrict__ deg,
                        int E, int halfN, int tiles) {
    __shared__ int cnt[NBIN];
    int t0 = blockIdx.x * TILE;
    for (int l = threadIdx.x; l < NBIN; l += NT) cnt[l] = 0;
    __syncthreads();
    for (int k = 0; k < TILE / (NT * 4); ++k) {
        int idx = t0 + (k * NT + threadIdx.x) * 4;
        if (idx + 3 < E) {
            int4 d4 = ldnt4(dst + idx);
            int4 s4 = ldnt4(src + idx);
            atomicAdd(&cnt[((d4.x >> B2) << 1) | (s4.x >= halfN)], 1);
            atomicAdd(&cnt[((d4.y >> B2) << 1) | (s4.y >= halfN)], 1);
            atomicAdd(&cnt[((d4.z >> B2) << 1) | (s4.z >= halfN)], 1);
            atomicAdd(&cnt[((d4.w >> B2) << 1) | (s4.w >= halfN)], 1);
            atomicAdd(&deg[d4.x], 1);
            atomicAdd(&deg[d4.y], 1);
            atomicAdd(&deg[d4.z], 1);
            atomicAdd(&deg[d4.w], 1);
        } else {
            for (int j = 0; j < 4; ++j)
                if (idx + j < E) {
                    int s = src[idx + j], d = dst[idx + j];
                    atomicAdd(&cnt[((d >> B2) << 1) | (s >= halfN)], 1);
                    atomicAdd(&deg[d], 1);
                }
        }
    }
    __syncthreads();
    for (int l = threadIdx.x; l < NBIN; l += NT)
        cntmat[l * tiles + blockIdx.x] = cnt[l];
}

// ===== k_scanA: per-bin exclusive prefix across tiles (in place) + totals =====
__global__ void __launch_bounds__(256)
k_scanA(int* __restrict__ cntmat, int* __restrict__ ghist, int tiles) {
    __shared__ int lds[256];
    int bin = blockIdx.x;
    int* row = cntmat + (size_t)bin * tiles;
    int tid = threadIdx.x;
    int carry = 0;
    for (int base = 0; base < tiles; base += 256) {
        int i = base + tid;
        int v = (i < tiles) ? row[i] : 0;
        lds[tid] = v;
        __syncthreads();
        for (int off = 1; off < 256; off <<= 1) {
            int t = (tid >= off) ? lds[tid - off] : 0;
            __syncthreads();
            lds[tid] += t;
            __syncthreads();
        }
        int incl = lds[tid];
        int tot = lds[255];
        if (i < tiles) row[i] = carry + incl - v;   // exclusive prefix
        carry += tot;
        __syncthreads();
    }
    if (tid == 0) ghist[bin] = carry;
}

// ===== k_scanB: padded (x4) exclusive scan over bin totals -> gbase =====
__global__ void k_scanB(const int* __restrict__ ghist, int* __restrict__ gbase) {
    __shared__ int part[NBIN];
    int tid = threadIdx.x;
    int t = ghist[tid];
    int p = (t + 3) & ~3;                  // padded size
    part[tid] = p;
    __syncthreads();
    for (int off = 1; off < NBIN; off <<= 1) {
        int v = (tid >= off) ? part[tid - off] : 0;
        __syncthreads();
        part[tid] += v;
        __syncthreads();
    }
    gbase[tid] = part[tid] - p;
    if (tid == NBIN - 1) gbase[NBIN] = part[NBIN - 1];
}

// ===== fill pad gaps with sentinels (disjoint from k_place's writes) =====
__global__ void k_pad(const int* __restrict__ ghist, const int* __restrict__ gbase,
                      int* __restrict__ pairs) {
    int b = threadIdx.x;
    int e = gbase[b] + ghist[b];
    int nxt = gbase[b + 1];
    for (; e < nxt; ++e) pairs[e] = SENT;
}

// ====== k_place: deterministic chunk bases from matrix; 1 LDS atomic/edge =====
__global__ void __launch_bounds__(512)
k_place(const int* __restrict__ src, const int* __restrict__ dst,
        const int* __restrict__ cntmat, const int* __restrict__ ghist,
        const int* __restrict__ gbase, int* __restrict__ pairs,
        int E, int halfN, int tiles) {
    __shared__ int cur[NBIN], gposc[NBIN];
    __shared__ int lbase2[NBIN + 1];
    __shared__ int part[512];
    __shared__ int lbuf[TILE];
    __shared__ int totalSh;
    int tile = blockIdx.x;
    int t0 = tile * TILE;
    int tid = threadIdx.x;
    int bA = 2 * tid, bB = 2 * tid + 1;
    int p00 = cntmat[(size_t)bA * tiles + tile];
    int p01 = (tile + 1 < tiles) ? cntmat[(size_t)bA * tiles + tile + 1] : ghist[bA];
    int p10 = cntmat[(size_t)bB * tiles + tile];
    int p11 = (tile + 1 < tiles) ? cntmat[(size_t)bB * tiles + tile + 1] : ghist[bB];
    int c0 = p01 - p00, c1 = p11 - p10;
    gposc[bA] = gbase[bA] + p00;
    gposc[bB] = gbase[bB] + p10;
    int t = c0 + c1;
    part[tid] = t;
    __syncthreads();
    for (int off = 1; off < 512; off <<= 1) {
        int v = (tid >= off) ? part[tid - off] : 0;
        __syncthreads();
        part[tid] += v;
        __syncthreads();
    }
    int ex = part[tid] - t;
    lbase2[bA] = ex;      cur[bA] = ex;
    lbase2[bB] = ex + c0; cur[bB] = ex + c0;
    if (tid == 511) { lbase2[NBIN] = part[511]; totalSh = part[511]; }
    __syncthreads();
    // place into LDS sorted by bin
    for (int k = 0; k < TILE / (512 * 4); ++k) {
        int idx = t0 + (k * 512 + tid) * 4;
        if (idx + 3 < E) {
            int4 s4 = ldnt4(src + idx);
            int4 d4 = ldnt4(dst + idx);
            int b, sl;
            b = ((d4.x >> B2) << 1) | (s4.x >= halfN); sl = atomicAdd(&cur[b], 1);
            lbuf[sl] = s4.x | ((d4.x & (BN - 1)) << 20);
            b = ((d4.y >> B2) << 1) | (s4.y >= halfN); sl = atomicAdd(&cur[b], 1);
            lbuf[sl] = s4.y | ((d4.y & (BN - 1)) << 20);
            b = ((d4.z >> B2) << 1) | (s4.z >= halfN); sl = atomicAdd(&cur[b], 1);
            lbuf[sl] = s4.z | ((d4.z & (BN - 1)) << 20);
            b = ((d4.w >> B2) << 1) | (s4.w >= halfN); sl = atomicAdd(&cur[b], 1);
            lbuf[sl] = s4.w | ((d4.w & (BN - 1)) << 20);
        } else {
            for (int j = 0; j < 4; ++j) {
                if (idx + j < E) {
                    int s = src[idx + j], d = dst[idx + j];
                    int b = ((d >> B2) << 1) | (s >= halfN);
                    int sl = atomicAdd(&cur[b], 1);
                    lbuf[sl] = s | ((d & (BN - 1)) << 20);
                }
            }
        }
    }
    __syncthreads();
    // coalesced copy-out via binary search in lbase2
    int total = totalSh;
    for (int idx = tid; idx < total; idx += 512) {
        int lo = 0, hi = NBIN - 1;
        while (lo < hi) {
            int mid = (lo + hi + 1) >> 1;
            if (lbase2[mid] <= idx) lo = mid; else hi = mid - 1;
        }
        pairs[gposc[lo] + (idx - lbase2[lo])] = lbuf[idx];
    }
}

// ========== k_prepy: elementwise dinv + y16 from deg (no atomics) ==========
__global__ void k_prepy(const int* __restrict__ deg, const float2* __restrict__ x,
                        float* __restrict__ dinv, unsigned* __restrict__ y16, int N) {
    int i = blockIdx.x * blockDim.x + threadIdx.x;
    if (i >= N) return;
    float di = rsqrtf((float)(deg[i] + 1));
    dinv[i] = di;
    float2 xi = ldnt2f((const float*)(x + i));
    y16[i] = f2h2(xi.x * di, xi.y * di);
}

// ========== layer1 agg: ONE ds_pk_add_f16 per edge (raw half2 bits) ==========
__global__ void __launch_bounds__(AT)
k_bagg1(const int* __restrict__ pairs, const int* __restrict__ gbase,
        const unsigned* __restrict__ y16, const float2* __restrict__ x,
        const float* __restrict__ dinv,
        const float* __restrict__ W1, const float* __restrict__ b1,
        const float* __restrict__ W2,
        float2* __restrict__ partA, float* __restrict__ partB,
        uint2* __restrict__ hfull, int N) {
    __shared__ unsigned accH[BN];
    int b = blockIdx.x, tid = threadIdx.x;
    int eBeg = gbase[2 * b], eEnd = gbase[2 * b + 2];
    for (int l = tid; l < BN; l += AT) accH[l] = 0u;
    __syncthreads();
    for (int idx = eBeg + (tid << 3); idx < eEnd; idx += AT * 8) {
        int4 a = ldnt4(pairs + idx);
        int idx2 = idx + 4;
        int4 bb;
        if (idx2 < eEnd) bb = ldnt4(pairs + idx2);
        else { bb.x = SENT; bb.y = SENT; bb.z = SENT; bb.w = SENT; }
        int sv[8] = {a.x, a.y, a.z, a.w, bb.x, bb.y, bb.z, bb.w};
        unsigned rv[8];
        #pragma unroll
        for (int q = 0; q < 8; ++q)
            rv[q] = y16[sv[q] & 0xFFFFF];
        #pragma unroll
        for (int q = 0; q < 8; ++q) {
            unsigned data = (sv[q] >= 0) ? rv[q] : 0u;
            int dl = (((unsigned)sv[q]) >> 20) & (BN - 1);
            pk_add_lds(&accH[dl], data);
        }
    }
    __syncthreads();
    int base = b << B2;
    for (int j = tid; j < BN; j += AT) {
        int i = base + j;
        if (i >= N) continue;
        float2 a = h2f2(accH[j]);
        float di = dinv[i];
        float2 xi = ldnt2f((const float*)(x + i));
        float ay0 = a.x + xi.x * di;       // self loop fp32
        float ay1 = a.y + xi.y * di;
        float o0 = fmaxf(di * (ay0 * W1[0] + ay1 * W1[4]) + b1[0], 0.f);
        float o1 = fmaxf(di * (ay0 * W1[1] + ay1 * W1[5]) + b1[1], 0.f);
        float o2 = fmaxf(di * (ay0 * W1[2] + ay1 * W1[6]) + b1[2], 0.f);
        float o3 = fmaxf(di * (ay0 * W1[3] + ay1 * W1[7]) + b1[3], 0.f);
        float h0 = (o0 * W2[0] + o1 * W2[3] + o2 * W2[6] + o3 * W2[9])  * di;
        float h1 = (o0 * W2[1] + o1 * W2[4] + o2 * W2[7] + o3 * W2[10]) * di;
        float hv2 = (o0 * W2[2] + o1 * W2[5] + o2 * W2[8] + o3 * W2[11]) * di;
        // self-loop running sums (fp32) for layer 2
        v2f sA; sA.x = h0; sA.y = h1;
        __builtin_nontemporal_store(sA, (v2f*)(partA + i));
        __builtin_nontemporal_store(hv2, partB + i);
        // packed half4 gather record: ONE 8B load per edge in layer 2
        uint2 hp; hp.x = f2h2(h0, h1); hp.y = f2h2(hv2, 0.f);
        hfull[i] = hp;
    }
}

// ===== layer2 phase LO: src < halfN edges, 4MB L2-resident gather region =====
__global__ void __launch_bounds__(AT)
k_bagg2lo(const int* __restrict__ pairs, const int* __restrict__ gbase,
          const uint2* __restrict__ hfull,
          float2* __restrict__ partA, float* __restrict__ partB, int N) {
    __shared__ unsigned acc01[BN];
    __shared__ float acc2[BN];
    int b = blockIdx.x, tid = threadIdx.x;
    int eBeg = gbase[2 * b], eEnd = gbase[2 * b + 1];
    for (int l = tid; l < BN; l += AT) { acc01[l] = 0u; acc2[l] = 0.f; }
    __syncthreads();
    for (int idx = eBeg + (tid << 3); idx < eEnd; idx += AT * 8) {
        int4 a = ldnt4(pairs + idx);
        int idx2 = idx + 4;
        int4 bb;
        if (idx2 < eEnd) bb = ldnt4(pairs + idx2);
        else { bb.x = SENT; bb.y = SENT; bb.z = SENT; bb.w = SENT; }
        int sv[8] = {a.x, a.y, a.z, a.w, bb.x, bb.y, bb.z, bb.w};
        uint2 r[8];
        #pragma unroll
        for (int q = 0; q < 8; ++q)
            r[q] = hfull[sv[q] & 0xFFFFF];
        #pragma unroll
        for (int q = 0; q < 8; ++q) {
            int dl = (((unsigned)sv[q]) >> 20) & (BN - 1);
            unsigned d01 = (sv[q] >= 0) ? r[q].x : 0u;
            float    f2v = (sv[q] >= 0) ? h2f2(r[q].y).x : 0.f;
            pk_add_lds(&acc01[dl], d01);
            atomicAdd(&acc2[dl], f2v);
        }
    }
    __syncthreads();
    int base = b << B2;
    for (int j = tid; j < BN; j += AT) {
        int i = base + j;
        if (i >= N) continue;
        float2 a01 = h2f2(acc01[j]);
        float2 pa = ldnt2f((const float*)(partA + i));
        float pb = __builtin_nontemporal_load(partB + i);
        v2f oA; oA.x = pa.x + a01.x; oA.y = pa.y + a01.y;
        __builtin_nontemporal_store(oA, (v2f*)(partA + i));
        __builtin_nontemporal_store(pb + acc2[j], partB + i);
    }
}

// ===== layer2 phase HI: src >= halfN edges + sigmoid + MLP epilogue =====
__global__ void __launch_bounds__(AT)
k_bagg2hi(const int* __restrict__ pairs, const int* __restrict__ gbase,
          const uint2* __restrict__ hfull,
          const float2* __restrict__ partA, const float* __restrict__ partB,
          const float* __restrict__ dinv,
          const float* __restrict__ b2,
          const float* __restrict__ W3, const float* __restrict__ b3,
          const float* __restrict__ W4, const float* __restrict__ b4,
          const float* __restrict__ W5, const float* __restrict__ b5,
          float* __restrict__ out, int N) {
    __shared__ unsigned acc01[BN];
    __shared__ float acc2[BN];
    int b = blockIdx.x, tid = threadIdx.x;
    int eBeg = gbase[2 * b + 1], eEnd = gbase[2 * b + 2];
    for (int l = tid; l < BN; l += AT) { acc01[l] = 0u; acc2[l] = 0.f; }
    __syncthreads();
    for (int idx = eBeg + (tid << 3); idx < eEnd; idx += AT * 8) {
        int4 a = ldnt4(pairs + idx);
        int idx2 = idx + 4;
        int4 bb;
        if (idx2 < eEnd) bb = ldnt4(pairs + idx2);
        else { bb.x = SENT; bb.y = SENT; bb.z = SENT; bb.w = SENT; }
        int sv[8] = {a.x, a.y, a.z, a.w, bb.x, bb.y, bb.z, bb.w};
        uint2 r[8];
        #pragma unroll
        for (int q = 0; q < 8; ++q)
            r[q] = hfull[sv[q] & 0xFFFFF];
        #pragma unroll
        for (int q = 0; q < 8; ++q) {
            int dl = (((unsigned)sv[q]) >> 20) & (BN - 1);
            unsigned d01 = (sv[q] >= 0) ? r[q].x : 0u;
            float    f2v = (sv[q] >= 0) ? h2f2(r[q].y).x : 0.f;
            pk_add_lds(&acc01[dl], d01);
            atomicAdd(&acc2[dl], f2v);
        }
    }
    __syncthreads();
    int base = b << B2;
    for (int j = tid; j < BN; j += AT) {
        int i = base + j;
        if (i >= N) continue;
        float2 a01 = h2f2(acc01[j]);
        float2 pa = ldnt2f((const float*)(partA + i));
        float pb = __builtin_nontemporal_load(partB + i);
        float s0 = pa.x + a01.x;
        float s1 = pa.y + a01.y;
        float s2 = pb + acc2[j];
        float di = __builtin_nontemporal_load(dinv + i);
        float z0 = di * s0 + b2[0];
        float z1 = di * s1 + b2[1];
        float z2 = di * s2 + b2[2];
        float g0 = 1.f / (1.f + expf(-z0));
        float g1 = 1.f / (1.f + expf(-z1));
        float g2 = 1.f / (1.f + expf(-z2));
        float t0 = fmaxf(g0 * W3[0] + g1 * W3[4] + g2 * W3[8]  + b3[0], 0.f);
        float t1 = fmaxf(g0 * W3[1] + g1 * W3[5] + g2 * W3[9]  + b3[1], 0.f);
        float t2 = fmaxf(g0 * W3[2] + g1 * W3[6] + g2 * W3[10] + b3[2], 0.f);
        float t3 = fmaxf(g0 * W3[3] + g1 * W3[7] + g2 * W3[11] + b3[3], 0.f);
        float u0 = fmaxf(t0 * W4[0] + t1 * W4[3] + t2 * W4[6] + t3 * W4[9]  + b4[0], 0.f);
        float u1 = fmaxf(t0 * W4[1] + t1 * W4[4] + t2 * W4[7] + t3 * W4[10] + b4[1], 0.f);
        float u2 = fmaxf(t0 * W4[2] + t1 * W4[5] + t2 * W4[8] + t3 * W4[11] + b4[2], 0.f);
        out[i] = u0 * W5[0] + u1 * W5[1] + u2 * W5[2] + b5[0];
    }
}

// ================= fallback path (round-2 global CSR, fp32) =================
__global__ void k_deg(const int* __restrict__ dst, int* __restrict__ deg, int E) {
    int e = blockIdx.x * blockDim.x + threadIdx.x;
    if (e < E) atomicAdd(deg + dst[e], 1);
}
__global__ void k_scan1(const int* __restrict__ deg, int* __restrict__ row,
                        int* __restrict__ bsum, int N) {
    __shared__ int lds[NT];
    int base = blockIdx.x * SCAN_E + threadIdx.x * 4;
    int d0 = 0, d1 = 0, d2 = 0, d3 = 0;
    if (base + 3 < N) {
        int4 v = *(const int4*)(deg + base);
        d0 = v.x; d1 = v.y; d2 = v.z; d3 = v.w;
    } else {
        if (base     < N) d0 = deg[base];
        if (base + 1 < N) d1 = deg[base + 1];
        if (base + 2 < N) d2 = deg[base + 2];
        if (base + 3 < N) d3 = deg[base + 3];
    }
    int t = d0 + d1 + d2 + d3;
    lds[threadIdx.x] = t;
    __syncthreads();
    for (int off = 1; off < NT; off <<= 1) {
        int v = (threadIdx.x >= off) ? lds[threadIdx.x - off] : 0;
        __syncthreads();
        lds[threadIdx.x] += v;
        __syncthreads();
    }
    int excl = lds[threadIdx.x] - t;
    if (threadIdx.x == NT - 1) bsum[blockIdx.x] = lds[NT - 1];
    if (base     < N) row[base]     = excl;
    if (base + 1 < N) row[base + 1] = excl + d0;
    if (base + 2 < N) row[base + 2] = excl + d0 + d1;
    if (base + 3 < N) row[base + 3] = excl + d0 + d1 + d2;
}
__global__ void k_scan2(int* __restrict__ bsum, int M) {
    __shared__ int lds[NT];
    int base = threadIdx.x * 4;
    int d0 = 0, d1 = 0, d2 = 0, d3 = 0;
    if (base     < M) d0 = bsum[base];
    if (base + 1 < M) d1 = bsum[base + 1];
    if (base + 2 < M) d2 = bsum[base + 2];
    if (base + 3 < M) d3 = bsum[base + 3];
    int t = d0 + d1 + d2 + d3;
    lds[threadIdx.x] = t;
    __syncthreads();
    for (int off = 1; off < NT; off <<= 1) {
        int v = (threadIdx.x >= off) ? lds[threadIdx.x - off] : 0;
        __syncthreads();
        lds[threadIdx.x] += v;
        __syncthreads();
    }
    int excl = lds[threadIdx.x] - t;
    if (base     < M) bsum[base]     = excl;
    if (base + 1 < M) bsum[base + 1] = excl + d0;
    if (base + 2 < M) bsum[base + 2] = excl + d0 + d1;
    if (base + 3 < M) bsum[base + 3] = excl + d0 + d1 + d2;
}
__global__ void k_scan3(int* __restrict__ row, const int* __restrict__ bsum, int N) {
    int base = blockIdx.x * SCAN_E + threadIdx.x * 4;
    int add = bsum[blockIdx.x];
    if (base + 3 < N) {
        int4 v = *(int4*)(row + base);
        v.x += add; v.y += add; v.z += add; v.w += add;
        *(int4*)(row + base) = v;
    } else {
        if (base     < N) row[base]     += add;
        if (base + 1 < N) row[base + 1] += add;
        if (base + 2 < N) row[base + 2] += add;
    }
}
__global__ void k_scatter(const int* __restrict__ src, const int* __restrict__ dst,
                          int* __restrict__ row, int* __restrict__ ss, int E) {
    int e = blockIdx.x * blockDim.x + threadIdx.x;
    if (e >= E) return;
    int s = src[e], d = dst[e];
    int slot = atomicAdd(row + d, 1);
    ss[slot] = s;
}
__global__ void k_node1_fb(const float2* __restrict__ x, const int* __restrict__ deg,
                           const float* __restrict__ W1,
                           float* __restrict__ dinv, float4* __restrict__ hp, int N) {
    int i = blockIdx.x * blockDim.x + threadIdx.x;
    if (i >= N) return;
    float2 xi = x[i];
    float di = rsqrtf((float)(deg[i] + 1));
    dinv[i] = di;
    float4 h;
    h.x = (xi.x * W1[0] + xi.y * W1[4]) * di;
    h.y = (xi.x * W1[1] + xi.y * W1[5]) * di;
    h.z = (xi.x * W1[2] + xi.y * W1[6]) * di;
    h.w = (xi.x * W1[3] + xi.y * W1[7]) * di;
    hp[i] = h;
}
__global__ void k_aggf1_fb(const int* __restrict__ row, const int* __restrict__ ss,
                           const float4* __restrict__ hp1, const float* __restrict__ dinv,
                           const float* __restrict__ b1, const float* __restrict__ W2,
                           float4* __restrict__ hp2, int N) {
    int i = blockIdx.x * blockDim.x + threadIdx.x;
    if (i >= N) return;
    int beg = (i == 0) ? 0 : row[i - 1];
    int end = row[i];
    float4 a = hp1[i];
    for (int e = beg; e < end; ++e) {
        float4 ha = hp1[ss[e]];
        a.x += ha.x; a.y += ha.y; a.z += ha.z; a.w += ha.w;
    }
    float di = dinv[i];
    float o0 = fmaxf(di * a.x + b1[0], 0.f);
    float o1 = fmaxf(di * a.y + b1[1], 0.f);
    float o2 = fmaxf(di * a.z + b1[2], 0.f);
    float o3 = fmaxf(di * a.w + b1[3], 0.f);
    float4 h;
    h.x = (o0 * W2[0] + o1 * W2[3] + o2 * W2[6] + o3 * W2[9])  * di;
    h.y = (o0 * W2[1] + o1 * W2[4] + o2 * W2[7] + o3 * W2[10]) * di;
    h.z = (o0 * W2[2] + o1 * W2[5] + o2 * W2[8] + o3 * W2[11]) * di;
    h.w = 0.f;
    hp2[i] = h;
}
__global__ void k_aggf2_fb(const int* __restrict__ row, const int* __restrict__ ss,
                           const float4* __restrict__ hp2, const float* __restrict__ dinv,
                           const float* __restrict__ b2,
                           const float* __restrict__ W3, const float* __restrict__ b3,
                           const float* __restrict__ W4, const float* __restrict__ b4,
                           const float* __restrict__ W5, const float* __restrict__ b5,
                           float* __restrict__ out, int N) {
    int i = blockIdx.x * blockDim.x + threadIdx.x;
    if (i >= N) return;
    int beg = (i == 0) ? 0 : row[i - 1];
    int end = row[i];
    float4 a = hp2[i];
    for (int e = beg; e < end; ++e) {
        float4 ha = hp2[ss[e]];
        a.x += ha.x; a.y += ha.y; a.z += ha.z;
    }
    float di = dinv[i];
    float z0 = di * a.x + b2[0];
    float z1 = di * a.y + b2[1];
    float z2 = di * a.z + b2[2];
    float g0 = 1.f / (1.f + expf(-z0));
    float g1 = 1.f / (1.f + expf(-z1));
    float g2 = 1.f / (1.f + expf(-z2));
    float t0 = fmaxf(g0 * W3[0] + g1 * W3[4] + g2 * W3[8]  + b3[0], 0.f);
    float t1 = fmaxf(g0 * W3[1] + g1 * W3[5] + g2 * W3[9]  + b3[1], 0.f);
    float t2 = fmaxf(g0 * W3[2] + g1 * W3[6] + g2 * W3[10] + b3[2], 0.f);
    float t3 = fmaxf(g0 * W3[3] + g1 * W3[7] + g2 * W3[11] + b3[3], 0.f);
    float u0 = fmaxf(t0 * W4[0] + t1 * W4[3] + t2 * W4[6] + t3 * W4[9]  + b4[0], 0.f);
    float u1 = fmaxf(t0 * W4[1] + t1 * W4[4] + t2 * W4[7] + t3 * W4[10] + b4[1], 0.f);
    float u2 = fmaxf(t0 * W4[2] + t1 * W4[5] + t2 * W4[8] + t3 * W4[11] + b4[2], 0.f);
    out[i] = u0 * W5[0] + u1 * W5[1] + u2 * W5[2] + b5[0];
}

extern "C" void kernel_launch(void* const* d_in, const int* in_sizes, int n_in,
                              void* d_out, int out_size, void* d_ws, size_t ws_size,
                              hipStream_t stream) {
    const float* x  = (const float*)d_in[0];
    const int*   ei = (const int*)d_in[1];
    const float* W1 = (const float*)d_in[2];
    const float* b1 = (const float*)d_in[3];
    const float* W2 = (const float*)d_in[4];
    const float* b2 = (const float*)d_in[5];
    const float* W3 = (const float*)d_in[6];
    const float* b3 = (const float*)d_in[7];
    const float* W4 = (const float*)d_in[8];
    const float* b4 = (const float*)d_in[9];
    const float* W5 = (const float*)d_in[10];
    const float* b5 = (const float*)d_in[11];

    const int N = in_sizes[0] / 2;
    const int E = in_sizes[1] / 2;
    const int* src = ei;
    const int* dst = ei + E;

    const int gbN = (N + NT - 1) / NT;
    const int gbE = (E + NT - 1) / NT;
    const int tiles = (E + TILE - 1) / TILE;
    const int NB = (N + BN - 1) >> B2;
    const int halfN = (N + 1) >> 1;

    char* ws = (char*)d_ws;

    // -------- primary: matrix-scan sort (count once) + per-bucket LDS agg ----
    size_t szPairs  = (size_t)(E + 4 * NBIN) * 4;
    size_t offPartA = (szPairs + 15) & ~(size_t)15;
    size_t offPartB = offPartA + (size_t)N * 8;   // partB aliases deg (int)
    size_t offY16   = offPartB + (size_t)N * 4;
    size_t offDinv  = offY16 + (size_t)N * 4;
    size_t offHfull = offDinv + (size_t)N * 4;
    size_t offCnt   = (offHfull + (size_t)N * 8 + 15) & ~(size_t)15;
    size_t offHist  = (offCnt + (size_t)NBIN * tiles * 4 + 15) & ~(size_t)15;
    size_t need1    = offHist + (size_t)(2 * NBIN + 2) * 4 + 64;

    if (N <= (1 << 20) && NB <= NBMAX && ws_size >= need1) {
        int*      pairs  = (int*)ws;
        float2*   partA  = (float2*)(ws + offPartA);
        float*    partB  = (float*)(ws + offPartB);
        int*      deg    = (int*)(ws + offPartB);     // alias: freed before bagg1
        unsigned* y16    = (unsigned*)(ws + offY16);
        float*    dinv   = (float*)(ws + offDinv);
        uint2*    hfull  = (uint2*)(ws + offHfull);
        int*      cntmat = (int*)(ws + offCnt);
        int*      ghist  = (int*)(ws + offHist);
        int*      gbase  = ghist + NBIN;

        hipMemsetAsync(deg, 0, (size_t)N * 4, stream);
        k_count  <<<tiles, NT, 0, stream>>>(src, dst, cntmat, deg, E, halfN, tiles);
        k_scanA  <<<NBIN, 256, 0, stream>>>(cntmat, ghist, tiles);
        k_scanB  <<<1, NBIN, 0, stream>>>(ghist, gbase);
        k_pad    <<<1, NBIN, 0, stream>>>(ghist, gbase, pairs);
        k_place  <<<tiles, 512, 0, stream>>>(src, dst, cntmat, ghist, gbase,
                                             pairs, E, halfN, tiles);
        k_prepy  <<<(N + 255) / 256, 256, 0, stream>>>(deg, (const float2*)x,
                                                       dinv, y16, N);
        k_bagg1  <<<NB, AT, 0, stream>>>(pairs, gbase, y16, (const float2*)x,
                                         dinv, W1, b1, W2, partA, partB,
                                         hfull, N);
        k_bagg2lo<<<NB, AT, 0, stream>>>(pairs, gbase, hfull, partA, partB, N);
        k_bagg2hi<<<NB, AT, 0, stream>>>(pairs, gbase, hfull, partA, partB,
                                         dinv, b2, W3, b3, W4, b4, W5, b5,
                                         (float*)d_out, N);
        return;
    }

    // -------- fallback: global counting-sort CSR (fp32) --------
    const int nScanBlocks = (N + SCAN_E - 1) / SCAN_E;
    size_t need2 = (size_t)N * 44 + (size_t)E * 4 + (size_t)nScanBlocks * 4 + 256;
    if (ws_size >= need2 && nScanBlocks <= NT * 4) {
        float4* hp1  = (float4*)ws;
        float4* hp2  = (float4*)(ws + (size_t)N * 16);
        int*    ss   = (int*)   (ws + (size_t)N * 32);
        int*    deg  = (int*)   (ws + (size_t)N * 32 + (size_t)E * 4);
        int*    row  = (int*)   (ws + (size_t)N * 36 + (size_t)E * 4);
        float*  dinv = (float*) (ws + (size_t)N * 40 + (size_t)E * 4);
        int*    bsum = (int*)   (ws + (size_t)N * 44 + (size_t)E * 4);

        hipMemsetAsync(deg, 0, (size_t)N * 4, stream);
        k_deg     <<<gbE, NT, 0, stream>>>(dst, deg, E);
        k_scan1   <<<nScanBlocks, NT, 0, stream>>>(deg, row, bsum, N);
        k_scan2   <<<1, NT, 0, stream>>>(bsum, nScanBlocks);
        k_scan3   <<<nScanBlocks, NT, 0, stream>>>(row, bsum, N);
        k_node1_fb<<<gbN, NT, 0, stream>>>((const float2*)x, deg, W1, dinv, hp1, N);
        k_scatter <<<gbE, NT, 0, stream>>>(src, dst, row, ss, E);
        k_aggf1_fb<<<gbN, NT, 0, stream>>>(row, ss, hp1, dinv, b1, W2, hp2, N);
        k_aggf2_fb<<<gbN, NT, 0, stream>>>(row, ss, hp2, dinv, b2, W3, b3, W4, b4,
                                           W5, b5, (float*)d_out, N);
    }
}

// Round 6
// 618.752 us; speedup vs baseline: 1.9135x; 1.9135x over previous
//
#include <hip/hip_runtime.h>
#include <hip/hip_bf16.h>
#include <hip/hip_fp16.h>

// GCN, bucket-sorted edge list + per-bucket LDS-accumulator aggregation.
//  - MEASURED MODEL (r1-r5): per-edge work is LDS-ATOMIC-OP bound at ~5.5us
//    per M lane-ops (binscatter 32M=173.7us r4). Random GLOBAL atomics are
//    ~35us/M (r5 k_count deg atomics: 617us, WRITE 566MB) -- NEVER use them
//    per-edge. Optimize by DELETING counting passes, keeping all per-edge
//    atomics in LDS.
//  - count ONCE: k_count writes per-(bin,tile) counts to a global matrix
//    (8MB). k_scanA (per-bin prefix over tiles) + k_scanB (padded scan over
//    bins) give deterministic chunk bases -> k_place pays only the 16M
//    placement atomics (no recount, no gcur). binhist is eliminated.
//  - deg: computed in k_prep from sorted pairs via LDS count (r4-validated
//    ~90us). NOT via global atomics (r5 lesson).
//  - 1024 bins = (dst>>B2) x (src < N/2): layer 2 runs lo/hi phase kernels,
//    each gathering from a 4MB L2-fit half of hfull; ds_pk_add_f16 packs
//    ch0/ch1 into one LDS atomic (r4: -90us validated).
//  - bucket segments padded to x4 edges with sentinel 0x80000000; agg loops
//    branchless (sentinel -> add 0 at index 0).

constexpr int NT = 256;
constexpr int SCAN_E = 1024;   // fallback scan tile
constexpr int B2 = 11;
constexpr int BN = 1 << B2;    // 2048 nodes / bucket
constexpr int NBMAX = 512;     // max dst buckets
constexpr int NBIN = 1024;     // dst-bucket x src-half bins
constexpr int TILE = 8192;     // edges per partition tile
constexpr int AT = 1024;       // threads for per-bucket agg kernels
constexpr int SENT = (int)0x80000000;

typedef int   v4i __attribute__((ext_vector_type(4)));
typedef float v2f __attribute__((ext_vector_type(2)));

__device__ __forceinline__ int4 ldnt4(const int* p) {
    v4i v = __builtin_nontemporal_load((const v4i*)p);
    int4 r; r.x = v.x; r.y = v.y; r.z = v.z; r.w = v.w; return r;
}
__device__ __forceinline__ float2 ldnt2f(const float* p) {
    v2f v = __builtin_nontemporal_load((const v2f*)p);
    return make_float2(v.x, v.y);
}
__device__ __forceinline__ float2 h2f2(unsigned u) {
    __half2 h = __builtin_bit_cast(__half2, u);
    return __half22float2(h);
}
__device__ __forceinline__ unsigned f2h2(float a, float b) {
    return __builtin_bit_cast(unsigned, __floats2half2_rn(a, b));
}
// native packed-half LDS atomic add (gfx950 ds_pk_add_f16), fire-and-forget.
// __syncthreads() drains lgkmcnt(0), guaranteeing completion before epilogue.
__device__ __forceinline__ void pk_add_lds(unsigned* p, unsigned v) {
    asm volatile("ds_pk_add_f16 %0, %1"
                 :: "v"((unsigned)(size_t)p), "v"(v) : "memory");
}

// ========== k_count: per-(bin,tile) counts -> global matrix ==========
__global__ void k_count(const int* __restrict__ src, const int* __restrict__ dst,
                        int* __restrict__ cntmat, int E, int halfN, int tiles) {
    __shared__ int cnt[NBIN];
    int t0 = blockIdx.x * TILE;
    for (int l = threadIdx.x; l < NBIN; l += NT) cnt[l] = 0;
    __syncthreads();
    for (int k = 0; k < TILE / (NT * 4); ++k) {
        int idx = t0 + (k * NT + threadIdx.x) * 4;
        if (idx + 3 < E) {
            int4 d4 = ldnt4(dst + idx);
            int4 s4 = ldnt4(src + idx);
            atomicAdd(&cnt[((d4.x >> B2) << 1) | (s4.x >= halfN)], 1);
            atomicAdd(&cnt[((d4.y >> B2) << 1) | (s4.y >= halfN)], 1);
            atomicAdd(&cnt[((d4.z >> B2) << 1) | (s4.z >= halfN)], 1);
            atomicAdd(&cnt[((d4.w >> B2) << 1) | (s4.w >= halfN)], 1);
        } else {
            for (int j = 0; j < 4; ++j)
                if (idx + j < E) {
                    int s = src[idx + j], d = dst[idx + j];
                    atomicAdd(&cnt[((d >> B2) << 1) | (s >= halfN)], 1);
                }
        }
    }
    __syncthreads();
    for (int l = threadIdx.x; l < NBIN; l += NT)
        cntmat[l * tiles + blockIdx.x] = cnt[l];
}

// ===== k_scanA: per-bin exclusive prefix across tiles (in place) + totals =====
__global__ void __launch_bounds__(256)
k_scanA(int* __restrict__ cntmat, int* __restrict__ ghist, int tiles) {
    __shared__ int lds[256];
    int bin = blockIdx.x;
    int* row = cntmat + (size_t)bin * tiles;
    int tid = threadIdx.x;
    int carry = 0;
    for (int base = 0; base < tiles; base += 256) {
        int i = base + tid;
        int v = (i < tiles) ? row[i] : 0;
        lds[tid] = v;
        __syncthreads();
        for (int off = 1; off < 256; off <<= 1) {
            int t = (tid >= off) ? lds[tid - off] : 0;
            __syncthreads();
            lds[tid] += t;
            __syncthreads();
        }
        int incl = lds[tid];
        int tot = lds[255];
        if (i < tiles) row[i] = carry + incl - v;   // exclusive prefix
        carry += tot;
        __syncthreads();
    }
    if (tid == 0) ghist[bin] = carry;
}

// ===== k_scanB: padded (x4) exclusive scan over bin totals -> gbase =====
__global__ void k_scanB(const int* __restrict__ ghist, int* __restrict__ gbase) {
    __shared__ int part[NBIN];
    int tid = threadIdx.x;
    int t = ghist[tid];
    int p = (t + 3) & ~3;                  // padded size
    part[tid] = p;
    __syncthreads();
    for (int off = 1; off < NBIN; off <<= 1) {
        int v = (tid >= off) ? part[tid - off] : 0;
        __syncthreads();
        part[tid] += v;
        __syncthreads();
    }
    gbase[tid] = part[tid] - p;
    if (tid == NBIN - 1) gbase[NBIN] = part[NBIN - 1];
}

// ===== fill pad gaps with sentinels (disjoint from k_place's writes) =====
__global__ void k_pad(const int* __restrict__ ghist, const int* __restrict__ gbase,
                      int* __restrict__ pairs) {
    int b = threadIdx.x;
    int e = gbase[b] + ghist[b];
    int nxt = gbase[b + 1];
    for (; e < nxt; ++e) pairs[e] = SENT;
}

// ====== k_place: deterministic chunk bases from matrix; 1 LDS atomic/edge =====
__global__ void __launch_bounds__(512)
k_place(const int* __restrict__ src, const int* __restrict__ dst,
        const int* __restrict__ cntmat, const int* __restrict__ ghist,
        const int* __restrict__ gbase, int* __restrict__ pairs,
        int E, int halfN, int tiles) {
    __shared__ int cur[NBIN], gposc[NBIN];
    __shared__ int lbase2[NBIN + 1];
    __shared__ int part[512];
    __shared__ int lbuf[TILE];
    __shared__ int totalSh;
    int tile = blockIdx.x;
    int t0 = tile * TILE;
    int tid = threadIdx.x;
    int bA = 2 * tid, bB = 2 * tid + 1;
    int p00 = cntmat[(size_t)bA * tiles + tile];
    int p01 = (tile + 1 < tiles) ? cntmat[(size_t)bA * tiles + tile + 1] : ghist[bA];
    int p10 = cntmat[(size_t)bB * tiles + tile];
    int p11 = (tile + 1 < tiles) ? cntmat[(size_t)bB * tiles + tile + 1] : ghist[bB];
    int c0 = p01 - p00, c1 = p11 - p10;
    gposc[bA] = gbase[bA] + p00;
    gposc[bB] = gbase[bB] + p10;
    int t = c0 + c1;
    part[tid] = t;
    __syncthreads();
    for (int off = 1; off < 512; off <<= 1) {
        int v = (tid >= off) ? part[tid - off] : 0;
        __syncthreads();
        part[tid] += v;
        __syncthreads();
    }
    int ex = part[tid] - t;
    lbase2[bA] = ex;      cur[bA] = ex;
    lbase2[bB] = ex + c0; cur[bB] = ex + c0;
    if (tid == 511) { lbase2[NBIN] = part[511]; totalSh = part[511]; }
    __syncthreads();
    // place into LDS sorted by bin
    for (int k = 0; k < TILE / (512 * 4); ++k) {
        int idx = t0 + (k * 512 + tid) * 4;
        if (idx + 3 < E) {
            int4 s4 = ldnt4(src + idx);
            int4 d4 = ldnt4(dst + idx);
            int b, sl;
            b = ((d4.x >> B2) << 1) | (s4.x >= halfN); sl = atomicAdd(&cur[b], 1);
            lbuf[sl] = s4.x | ((d4.x & (BN - 1)) << 20);
            b = ((d4.y >> B2) << 1) | (s4.y >= halfN); sl = atomicAdd(&cur[b], 1);
            lbuf[sl] = s4.y | ((d4.y & (BN - 1)) << 20);
            b = ((d4.z >> B2) << 1) | (s4.z >= halfN); sl = atomicAdd(&cur[b], 1);
            lbuf[sl] = s4.z | ((d4.z & (BN - 1)) << 20);
            b = ((d4.w >> B2) << 1) | (s4.w >= halfN); sl = atomicAdd(&cur[b], 1);
            lbuf[sl] = s4.w | ((d4.w & (BN - 1)) << 20);
        } else {
            for (int j = 0; j < 4; ++j) {
                if (idx + j < E) {
                    int s = src[idx + j], d = dst[idx + j];
                    int b = ((d >> B2) << 1) | (s >= halfN);
                    int sl = atomicAdd(&cur[b], 1);
                    lbuf[sl] = s | ((d & (BN - 1)) << 20);
                }
            }
        }
    }
    __syncthreads();
    // coalesced copy-out via binary search in lbase2
    int total = totalSh;
    for (int idx = tid; idx < total; idx += 512) {
        int lo = 0, hi = NBIN - 1;
        while (lo < hi) {
            int mid = (lo + hi + 1) >> 1;
            if (lbase2[mid] <= idx) lo = mid; else hi = mid - 1;
        }
        pairs[gposc[lo] + (idx - lbase2[lo])] = lbuf[idx];
    }
}

// ========== per-bucket prep: deg (LDS count) -> dinv, y16 = half2(x*dinv) =====
__global__ void __launch_bounds__(AT)
k_prep(const int* __restrict__ pairs, const int* __restrict__ gbase,
       const float2* __restrict__ x,
       float* __restrict__ dinv, unsigned* __restrict__ y16, int N) {
    __shared__ int cnt[BN];
    int b = blockIdx.x, tid = threadIdx.x;
    int eBeg = gbase[2 * b], eEnd = gbase[2 * b + 2];
    for (int l = tid; l < BN; l += AT) cnt[l] = 0;
    __syncthreads();
    for (int idx = eBeg + (tid << 2); idx < eEnd; idx += AT * 4) {
        int4 v4 = ldnt4(pairs + idx);
        atomicAdd(&cnt[(((unsigned)v4.x) >> 20) & (BN - 1)], (v4.x >= 0) ? 1 : 0);
        atomicAdd(&cnt[(((unsigned)v4.y) >> 20) & (BN - 1)], (v4.y >= 0) ? 1 : 0);
        atomicAdd(&cnt[(((unsigned)v4.z) >> 20) & (BN - 1)], (v4.z >= 0) ? 1 : 0);
        atomicAdd(&cnt[(((unsigned)v4.w) >> 20) & (BN - 1)], (v4.w >= 0) ? 1 : 0);
    }
    __syncthreads();
    int base = b << B2;
    for (int j = tid; j < BN; j += AT) {
        int i = base + j;
        if (i < N) {
            float di = rsqrtf((float)(cnt[j] + 1));
            dinv[i] = di;
            float2 xi = ldnt2f((const float*)(x + i));
            y16[i] = f2h2(xi.x * di, xi.y * di);
        }
    }
}

// ========== layer1 agg: ONE ds_pk_add_f16 per edge (raw half2 bits) ==========
__global__ void __launch_bounds__(AT)
k_bagg1(const int* __restrict__ pairs, const int* __restrict__ gbase,
        const unsigned* __restrict__ y16, const float2* __restrict__ x,
        const float* __restrict__ dinv,
        const float* __restrict__ W1, const float* __restrict__ b1,
        const float* __restrict__ W2,
        float2* __restrict__ partA, float* __restrict__ partB,
        uint2* __restrict__ hfull, int N) {
    __shared__ unsigned accH[BN];
    int b = blockIdx.x, tid = threadIdx.x;
    int eBeg = gbase[2 * b], eEnd = gbase[2 * b + 2];
    for (int l = tid; l < BN; l += AT) accH[l] = 0u;
    __syncthreads();
    for (int idx = eBeg + (tid << 3); idx < eEnd; idx += AT * 8) {
        int4 a = ldnt4(pairs + idx);
        int idx2 = idx + 4;
        int4 bb;
        if (idx2 < eEnd) bb = ldnt4(pairs + idx2);
        else { bb.x = SENT; bb.y = SENT; bb.z = SENT; bb.w = SENT; }
        int sv[8] = {a.x, a.y, a.z, a.w, bb.x, bb.y, bb.z, bb.w};
        unsigned rv[8];
        #pragma unroll
        for (int q = 0; q < 8; ++q)
            rv[q] = y16[sv[q] & 0xFFFFF];
        #pragma unroll
        for (int q = 0; q < 8; ++q) {
            unsigned data = (sv[q] >= 0) ? rv[q] : 0u;
            int dl = (((unsigned)sv[q]) >> 20) & (BN - 1);
            pk_add_lds(&accH[dl], data);
        }
    }
    __syncthreads();
    int base = b << B2;
    for (int j = tid; j < BN; j += AT) {
        int i = base + j;
        if (i >= N) continue;
        float2 a = h2f2(accH[j]);
        float di = dinv[i];
        float2 xi = ldnt2f((const float*)(x + i));
        float ay0 = a.x + xi.x * di;       // self loop fp32
        float ay1 = a.y + xi.y * di;
        float o0 = fmaxf(di * (ay0 * W1[0] + ay1 * W1[4]) + b1[0], 0.f);
        float o1 = fmaxf(di * (ay0 * W1[1] + ay1 * W1[5]) + b1[1], 0.f);
        float o2 = fmaxf(di * (ay0 * W1[2] + ay1 * W1[6]) + b1[2], 0.f);
        float o3 = fmaxf(di * (ay0 * W1[3] + ay1 * W1[7]) + b1[3], 0.f);
        float h0 = (o0 * W2[0] + o1 * W2[3] + o2 * W2[6] + o3 * W2[9])  * di;
        float h1 = (o0 * W2[1] + o1 * W2[4] + o2 * W2[7] + o3 * W2[10]) * di;
        float hv2 = (o0 * W2[2] + o1 * W2[5] + o2 * W2[8] + o3 * W2[11]) * di;
        // self-loop running sums (fp32) for layer 2
        v2f sA; sA.x = h0; sA.y = h1;
        __builtin_nontemporal_store(sA, (v2f*)(partA + i));
        __builtin_nontemporal_store(hv2, partB + i);
        // packed half4 gather record: ONE 8B load per edge in layer 2
        uint2 hp; hp.x = f2h2(h0, h1); hp.y = f2h2(hv2, 0.f);
        hfull[i] = hp;
    }
}

// ===== layer2 phase LO: src < halfN edges, 4MB L2-resident gather region =====
__global__ void __launch_bounds__(AT)
k_bagg2lo(const int* __restrict__ pairs, const int* __restrict__ gbase,
          const uint2* __restrict__ hfull,
          float2* __restrict__ partA, float* __restrict__ partB, int N) {
    __shared__ unsigned acc01[BN];
    __shared__ float acc2[BN];
    int b = blockIdx.x, tid = threadIdx.x;
    int eBeg = gbase[2 * b], eEnd = gbase[2 * b + 1];
    for (int l = tid; l < BN; l += AT) { acc01[l] = 0u; acc2[l] = 0.f; }
    __syncthreads();
    for (int idx = eBeg + (tid << 3); idx < eEnd; idx += AT * 8) {
        int4 a = ldnt4(pairs + idx);
        int idx2 = idx + 4;
        int4 bb;
        if (idx2 < eEnd) bb = ldnt4(pairs + idx2);
        else { bb.x = SENT; bb.y = SENT; bb.z = SENT; bb.w = SENT; }
        int sv[8] = {a.x, a.y, a.z, a.w, bb.x, bb.y, bb.z, bb.w};
        uint2 r[8];
        #pragma unroll
        for (int q = 0; q < 8; ++q)
            r[q] = hfull[sv[q] & 0xFFFFF];
        #pragma unroll
        for (int q = 0; q < 8; ++q) {
            int dl = (((unsigned)sv[q]) >> 20) & (BN - 1);
            unsigned d01 = (sv[q] >= 0) ? r[q].x : 0u;
            float    f2v = (sv[q] >= 0) ? h2f2(r[q].y).x : 0.f;
            pk_add_lds(&acc01[dl], d01);
            atomicAdd(&acc2[dl], f2v);
        }
    }
    __syncthreads();
    int base = b << B2;
    for (int j = tid; j < BN; j += AT) {
        int i = base + j;
        if (i >= N) continue;
        float2 a01 = h2f2(acc01[j]);
        float2 pa = ldnt2f((const float*)(partA + i));
        float pb = __builtin_nontemporal_load(partB + i);
        v2f oA; oA.x = pa.x + a01.x; oA.y = pa.y + a01.y;
        __builtin_nontemporal_store(oA, (v2f*)(partA + i));
        __builtin_nontemporal_store(pb + acc2[j], partB + i);
    }
}

// ===== layer2 phase HI: src >= halfN edges + sigmoid + MLP epilogue =====
__global__ void __launch_bounds__(AT)
k_bagg2hi(const int* __restrict__ pairs, const int* __restrict__ gbase,
          const uint2* __restrict__ hfull,
          const float2* __restrict__ partA, const float* __restrict__ partB,
          const float* __restrict__ dinv,
          const float* __restrict__ b2,
          const float* __restrict__ W3, const float* __restrict__ b3,
          const float* __restrict__ W4, const float* __restrict__ b4,
          const float* __restrict__ W5, const float* __restrict__ b5,
          float* __restrict__ out, int N) {
    __shared__ unsigned acc01[BN];
    __shared__ float acc2[BN];
    int b = blockIdx.x, tid = threadIdx.x;
    int eBeg = gbase[2 * b + 1], eEnd = gbase[2 * b + 2];
    for (int l = tid; l < BN; l += AT) { acc01[l] = 0u; acc2[l] = 0.f; }
    __syncthreads();
    for (int idx = eBeg + (tid << 3); idx < eEnd; idx += AT * 8) {
        int4 a = ldnt4(pairs + idx);
        int idx2 = idx + 4;
        int4 bb;
        if (idx2 < eEnd) bb = ldnt4(pairs + idx2);
        else { bb.x = SENT; bb.y = SENT; bb.z = SENT; bb.w = SENT; }
        int sv[8] = {a.x, a.y, a.z, a.w, bb.x, bb.y, bb.z, bb.w};
        uint2 r[8];
        #pragma unroll
        for (int q = 0; q < 8; ++q)
            r[q] = hfull[sv[q] & 0xFFFFF];
        #pragma unroll
        for (int q = 0; q < 8; ++q) {
            int dl = (((unsigned)sv[q]) >> 20) & (BN - 1);
            unsigned d01 = (sv[q] >= 0) ? r[q].x : 0u;
            float    f2v = (sv[q] >= 0) ? h2f2(r[q].y).x : 0.f;
            pk_add_lds(&acc01[dl], d01);
            atomicAdd(&acc2[dl], f2v);
        }
    }
    __syncthreads();
    int base = b << B2;
    for (int j = tid; j < BN; j += AT) {
        int i = base + j;
        if (i >= N) continue;
        float2 a01 = h2f2(acc01[j]);
        float2 pa = ldnt2f((const float*)(partA + i));
        float pb = __builtin_nontemporal_load(partB + i);
        float s0 = pa.x + a01.x;
        float s1 = pa.y + a01.y;
        float s2 = pb + acc2[j];
        float di = __builtin_nontemporal_load(dinv + i);
        float z0 = di * s0 + b2[0];
        float z1 = di * s1 + b2[1];
        float z2 = di * s2 + b2[2];
        float g0 = 1.f / (1.f + expf(-z0));
        float g1 = 1.f / (1.f + expf(-z1));
        float g2 = 1.f / (1.f + expf(-z2));
        float t0 = fmaxf(g0 * W3[0] + g1 * W3[4] + g2 * W3[8]  + b3[0], 0.f);
        float t1 = fmaxf(g0 * W3[1] + g1 * W3[5] + g2 * W3[9]  + b3[1], 0.f);
        float t2 = fmaxf(g0 * W3[2] + g1 * W3[6] + g2 * W3[10] + b3[2], 0.f);
        float t3 = fmaxf(g0 * W3[3] + g1 * W3[7] + g2 * W3[11] + b3[3], 0.f);
        float u0 = fmaxf(t0 * W4[0] + t1 * W4[3] + t2 * W4[6] + t3 * W4[9]  + b4[0], 0.f);
        float u1 = fmaxf(t0 * W4[1] + t1 * W4[4] + t2 * W4[7] + t3 * W4[10] + b4[1], 0.f);
        float u2 = fmaxf(t0 * W4[2] + t1 * W4[5] + t2 * W4[8] + t3 * W4[11] + b4[2], 0.f);
        out[i] = u0 * W5[0] + u1 * W5[1] + u2 * W5[2] + b5[0];
    }
}

// ================= fallback path (round-2 global CSR, fp32) =================
__global__ void k_deg(const int* __restrict__ dst, int* __restrict__ deg, int E) {
    int e = blockIdx.x * blockDim.x + threadIdx.x;
    if (e < E) atomicAdd(deg + dst[e], 1);
}
__global__ void k_scan1(const int* __restrict__ deg, int* __restrict__ row,
                        int* __restrict__ bsum, int N) {
    __shared__ int lds[NT];
    int base = blockIdx.x * SCAN_E + threadIdx.x * 4;
    int d0 = 0, d1 = 0, d2 = 0, d3 = 0;
    if (base + 3 < N) {
        int4 v = *(const int4*)(deg + base);
        d0 = v.x; d1 = v.y; d2 = v.z; d3 = v.w;
    } else {
        if (base     < N) d0 = deg[base];
        if (base + 1 < N) d1 = deg[base + 1];
        if (base + 2 < N) d2 = deg[base + 2];
        if (base + 3 < N) d3 = deg[base + 3];
    }
    int t = d0 + d1 + d2 + d3;
    lds[threadIdx.x] = t;
    __syncthreads();
    for (int off = 1; off < NT; off <<= 1) {
        int v = (threadIdx.x >= off) ? lds[threadIdx.x - off] : 0;
        __syncthreads();
        lds[threadIdx.x] += v;
        __syncthreads();
    }
    int excl = lds[threadIdx.x] - t;
    if (threadIdx.x == NT - 1) bsum[blockIdx.x] = lds[NT - 1];
    if (base     < N) row[base]     = excl;
    if (base + 1 < N) row[base + 1] = excl + d0;
    if (base + 2 < N) row[base + 2] = excl + d0 + d1;
    if (base + 3 < N) row[base + 3] = excl + d0 + d1 + d2;
}
__global__ void k_scan2(int* __restrict__ bsum, int M) {
    __shared__ int lds[NT];
    int base = threadIdx.x * 4;
    int d0 = 0, d1 = 0, d2 = 0, d3 = 0;
    if (base     < M) d0 = bsum[base];
    if (base + 1 < M) d1 = bsum[base + 1];
    if (base + 2 < M) d2 = bsum[base + 2];
    if (base + 3 < M) d3 = bsum[base + 3];
    int t = d0 + d1 + d2 + d3;
    lds[threadIdx.x] = t;
    __syncthreads();
    for (int off = 1; off < NT; off <<= 1) {
        int v = (threadIdx.x >= off) ? lds[threadIdx.x - off] : 0;
        __syncthreads();
        lds[threadIdx.x] += v;
        __syncthreads();
    }
    int excl = lds[threadIdx.x] - t;
    if (base     < M) bsum[base]     = excl;
    if (base + 1 < M) bsum[base + 1] = excl + d0;
    if (base + 2 < M) bsum[base + 2] = excl + d0 + d1;
    if (base + 3 < M) bsum[base + 3] = excl + d0 + d1 + d2;
}
__global__ void k_scan3(int* __restrict__ row, const int* __restrict__ bsum, int N) {
    int base = blockIdx.x * SCAN_E + threadIdx.x * 4;
    int add = bsum[blockIdx.x];
    if (base + 3 < N) {
        int4 v = *(int4*)(row + base);
        v.x += add; v.y += add; v.z += add; v.w += add;
        *(int4*)(row + base) = v;
    } else {
        if (base     < N) row[base]     += add;
        if (base + 1 < N) row[base + 1] += add;
        if (base + 2 < N) row[base + 2] += add;
    }
}
__global__ void k_scatter(const int* __restrict__ src, const int* __restrict__ dst,
                          int* __restrict__ row, int* __restrict__ ss, int E) {
    int e = blockIdx.x * blockDim.x + threadIdx.x;
    if (e >= E) return;
    int s = src[e], d = dst[e];
    int slot = atomicAdd(row + d, 1);
    ss[slot] = s;
}
__global__ void k_node1_fb(const float2* __restrict__ x, const int* __restrict__ deg,
                           const float* __restrict__ W1,
                           float* __restrict__ dinv, float4* __restrict__ hp, int N) {
    int i = blockIdx.x * blockDim.x + threadIdx.x;
    if (i >= N) return;
    float2 xi = x[i];
    float di = rsqrtf((float)(deg[i] + 1));
    dinv[i] = di;
    float4 h;
    h.x = (xi.x * W1[0] + xi.y * W1[4]) * di;
    h.y = (xi.x * W1[1] + xi.y * W1[5]) * di;
    h.z = (xi.x * W1[2] + xi.y * W1[6]) * di;
    h.w = (xi.x * W1[3] + xi.y * W1[7]) * di;
    hp[i] = h;
}
__global__ void k_aggf1_fb(const int* __restrict__ row, const int* __restrict__ ss,
                           const float4* __restrict__ hp1, const float* __restrict__ dinv,
                           const float* __restrict__ b1, const float* __restrict__ W2,
                           float4* __restrict__ hp2, int N) {
    int i = blockIdx.x * blockDim.x + threadIdx.x;
    if (i >= N) return;
    int beg = (i == 0) ? 0 : row[i - 1];
    int end = row[i];
    float4 a = hp1[i];
    for (int e = beg; e < end; ++e) {
        float4 ha = hp1[ss[e]];
        a.x += ha.x; a.y += ha.y; a.z += ha.z; a.w += ha.w;
    }
    float di = dinv[i];
    float o0 = fmaxf(di * a.x + b1[0], 0.f);
    float o1 = fmaxf(di * a.y + b1[1], 0.f);
    float o2 = fmaxf(di * a.z + b1[2], 0.f);
    float o3 = fmaxf(di * a.w + b1[3], 0.f);
    float4 h;
    h.x = (o0 * W2[0] + o1 * W2[3] + o2 * W2[6] + o3 * W2[9])  * di;
    h.y = (o0 * W2[1] + o1 * W2[4] + o2 * W2[7] + o3 * W2[10]) * di;
    h.z = (o0 * W2[2] + o1 * W2[5] + o2 * W2[8] + o3 * W2[11]) * di;
    h.w = 0.f;
    hp2[i] = h;
}
__global__ void k_aggf2_fb(const int* __restrict__ row, const int* __restrict__ ss,
                           const float4* __restrict__ hp2, const float* __restrict__ dinv,
                           const float* __restrict__ b2,
                           const float* __restrict__ W3, const float* __restrict__ b3,
                           const float* __restrict__ W4, const float* __restrict__ b4,
                           const float* __restrict__ W5, const float* __restrict__ b5,
                           float* __restrict__ out, int N) {
    int i = blockIdx.x * blockDim.x + threadIdx.x;
    if (i >= N) return;
    int beg = (i == 0) ? 0 : row[i - 1];
    int end = row[i];
    float4 a = hp2[i];
    for (int e = beg; e < end; ++e) {
        float4 ha = hp2[ss[e]];
        a.x += ha.x; a.y += ha.y; a.z += ha.z;
    }
    float di = dinv[i];
    float z0 = di * a.x + b2[0];
    float z1 = di * a.y + b2[1];
    float z2 = di * a.z + b2[2];
    float g0 = 1.f / (1.f + expf(-z0));
    float g1 = 1.f / (1.f + expf(-z1));
    float g2 = 1.f / (1.f + expf(-z2));
    float t0 = fmaxf(g0 * W3[0] + g1 * W3[4] + g2 * W3[8]  + b3[0], 0.f);
    float t1 = fmaxf(g0 * W3[1] + g1 * W3[5] + g2 * W3[9]  + b3[1], 0.f);
    float t2 = fmaxf(g0 * W3[2] + g1 * W3[6] + g2 * W3[10] + b3[2], 0.f);
    float t3 = fmaxf(g0 * W3[3] + g1 * W3[7] + g2 * W3[11] + b3[3], 0.f);
    float u0 = fmaxf(t0 * W4[0] + t1 * W4[3] + t2 * W4[6] + t3 * W4[9]  + b4[0], 0.f);
    float u1 = fmaxf(t0 * W4[1] + t1 * W4[4] + t2 * W4[7] + t3 * W4[10] + b4[1], 0.f);
    float u2 = fmaxf(t0 * W4[2] + t1 * W4[5] + t2 * W4[8] + t3 * W4[11] + b4[2], 0.f);
    out[i] = u0 * W5[0] + u1 * W5[1] + u2 * W5[2] + b5[0];
}

extern "C" void kernel_launch(void* const* d_in, const int* in_sizes, int n_in,
                              void* d_out, int out_size, void* d_ws, size_t ws_size,
                              hipStream_t stream) {
    const float* x  = (const float*)d_in[0];
    const int*   ei = (const int*)d_in[1];
    const float* W1 = (const float*)d_in[2];
    const float* b1 = (const float*)d_in[3];
    const float* W2 = (const float*)d_in[4];
    const float* b2 = (const float*)d_in[5];
    const float* W3 = (const float*)d_in[6];
    const float* b3 = (const float*)d_in[7];
    const float* W4 = (const float*)d_in[8];
    const float* b4 = (const float*)d_in[9];
    const float* W5 = (const float*)d_in[10];
    const float* b5 = (const float*)d_in[11];

    const int N = in_sizes[0] / 2;
    const int E = in_sizes[1] / 2;
    const int* src = ei;
    const int* dst = ei + E;

    const int gbN = (N + NT - 1) / NT;
    const int gbE = (E + NT - 1) / NT;
    const int tiles = (E + TILE - 1) / TILE;
    const int NB = (N + BN - 1) >> B2;
    const int halfN = (N + 1) >> 1;

    char* ws = (char*)d_ws;

    // -------- primary: matrix-scan sort (count once) + per-bucket LDS agg ----
    size_t szPairs  = (size_t)(E + 4 * NBIN) * 4;
    size_t offPartA = (szPairs + 15) & ~(size_t)15;
    size_t offPartB = offPartA + (size_t)N * 8;
    size_t offY16   = offPartB + (size_t)N * 4;
    size_t offDinv  = offY16 + (size_t)N * 4;
    size_t offHfull = offDinv + (size_t)N * 4;
    size_t offCnt   = (offHfull + (size_t)N * 8 + 15) & ~(size_t)15;
    size_t offHist  = (offCnt + (size_t)NBIN * tiles * 4 + 15) & ~(size_t)15;
    size_t need1    = offHist + (size_t)(2 * NBIN + 2) * 4 + 64;

    if (N <= (1 << 20) && NB <= NBMAX && ws_size >= need1) {
        int*      pairs  = (int*)ws;
        float2*   partA  = (float2*)(ws + offPartA);
        float*    partB  = (float*)(ws + offPartB);
        unsigned* y16    = (unsigned*)(ws + offY16);
        float*    dinv   = (float*)(ws + offDinv);
        uint2*    hfull  = (uint2*)(ws + offHfull);
        int*      cntmat = (int*)(ws + offCnt);
        int*      ghist  = (int*)(ws + offHist);
        int*      gbase  = ghist + NBIN;

        k_count  <<<tiles, NT, 0, stream>>>(src, dst, cntmat, E, halfN, tiles);
        k_scanA  <<<NBIN, 256, 0, stream>>>(cntmat, ghist, tiles);
        k_scanB  <<<1, NBIN, 0, stream>>>(ghist, gbase);
        k_pad    <<<1, NBIN, 0, stream>>>(ghist, gbase, pairs);
        k_place  <<<tiles, 512, 0, stream>>>(src, dst, cntmat, ghist, gbase,
                                             pairs, E, halfN, tiles);
        k_prep   <<<NB, AT, 0, stream>>>(pairs, gbase, (const float2*)x,
                                         dinv, y16, N);
        k_bagg1  <<<NB, AT, 0, stream>>>(pairs, gbase, y16, (const float2*)x,
                                         dinv, W1, b1, W2, partA, partB,
                                         hfull, N);
        k_bagg2lo<<<NB, AT, 0, stream>>>(pairs, gbase, hfull, partA, partB, N);
        k_bagg2hi<<<NB, AT, 0, stream>>>(pairs, gbase, hfull, partA, partB,
                                         dinv, b2, W3, b3, W4, b4, W5, b5,
                                         (float*)d_out, N);
        return;
    }

    // -------- fallback: global counting-sort CSR (fp32) --------
    const int nScanBlocks = (N + SCAN_E - 1) / SCAN_E;
    size_t need2 = (size_t)N * 44 + (size_t)E * 4 + (size_t)nScanBlocks * 4 + 256;
    if (ws_size >= need2 && nScanBlocks <= NT * 4) {
        float4* hp1  = (float4*)ws;
        float4* hp2  = (float4*)(ws + (size_t)N * 16);
        int*    ss   = (int*)   (ws + (size_t)N * 32);
        int*    deg  = (int*)   (ws + (size_t)N * 32 + (size_t)E * 4);
        int*    row  = (int*)   (ws + (size_t)N * 36 + (size_t)E * 4);
        float*  dinv = (float*) (ws + (size_t)N * 40 + (size_t)E * 4);
        int*    bsum = (int*)   (ws + (size_t)N * 44 + (size_t)E * 4);

        hipMemsetAsync(deg, 0, (size_t)N * 4, stream);
        k_deg     <<<gbE, NT, 0, stream>>>(dst, deg, E);
        k_scan1   <<<nScanBlocks, NT, 0, stream>>>(deg, row, bsum, N);
        k_scan2   <<<1, NT, 0, stream>>>(bsum, nScanBlocks);
        k_scan3   <<<nScanBlocks, NT, 0, stream>>>(row, bsum, N);
        k_node1_fb<<<gbN, NT, 0, stream>>>((const float2*)x, deg, W1, dinv, hp1, N);
        k_scatter <<<gbE, NT, 0, stream>>>(src, dst, row, ss, E);
        k_aggf1_fb<<<gbN, NT, 0, stream>>>(row, ss, hp1, dinv, b1, W2, hp2, N);
        k_aggf2_fb<<<gbN, NT, 0, stream>>>(row, ss, hp2, dinv, b2, W3, b3, W4, b4,
                                           W5, b5, (float*)d_out, N);
    }
}

// Round 7
// 610.172 us; speedup vs baseline: 1.9404x; 1.0141x over previous
//
#include <hip/hip_runtime.h>
#include <hip/hip_bf16.h>
#include <hip/hip_fp16.h>

// GCN, bucket-sorted edge list + per-bucket LDS-accumulator aggregation.
//  - MEASURED MODEL (r1-r6): dur ~= max(LDS-atomic lane-ops x 5.6us/M,
//    gather lines x 6.3us/M) per kernel. The LDS-atomic unit is PER-CU
//    SERIALIZED (~3.6cyc/lane-op; occupancy-invariant, r0 vs r2).
//    Random GLOBAL atomics are ~35us/M (r5) -- never per-edge.
//    Op ledger at floor: sort 2/edge + deg 1 + L1 1 + L2 2 = 96M ops.
//  - count ONCE: k_count -> per-(bin,tile) matrix; k_scanA/B -> deterministic
//    chunk bases; k_place pays only placement atomics. No binhist, no gcur.
//  - deg via k_prep LDS count from sorted pairs (r4-validated).
//  - 1024 bins = (dst>>B2) x (src < N/2): layer 2 lo/hi phases, each gathering
//    a 4MB L2-resident half of hfull; ds_pk_add_f16 packs ch0/ch1 (r4: -90us).
//  - r7: k_place copy-out uses u16 lbins side-array (bin recorded at placement)
//    instead of 13-step binary search: -208M LDS reads ~= -25us.
//  - bucket segments padded to x4 edges with sentinel 0x80000000; agg loops
//    branchless (sentinel -> add 0 at index 0).

constexpr int NT = 256;
constexpr int SCAN_E = 1024;   // fallback scan tile
constexpr int B2 = 11;
constexpr int BN = 1 << B2;    // 2048 nodes / bucket
constexpr int NBMAX = 512;     // max dst buckets
constexpr int NBIN = 1024;     // dst-bucket x src-half bins
constexpr int TILE = 8192;     // edges per partition tile
constexpr int AT = 1024;       // threads for per-bucket agg kernels
constexpr int SENT = (int)0x80000000;

typedef int   v4i __attribute__((ext_vector_type(4)));
typedef float v2f __attribute__((ext_vector_type(2)));

__device__ __forceinline__ int4 ldnt4(const int* p) {
    v4i v = __builtin_nontemporal_load((const v4i*)p);
    int4 r; r.x = v.x; r.y = v.y; r.z = v.z; r.w = v.w; return r;
}
__device__ __forceinline__ float2 ldnt2f(const float* p) {
    v2f v = __builtin_nontemporal_load((const v2f*)p);
    return make_float2(v.x, v.y);
}
__device__ __forceinline__ float2 h2f2(unsigned u) {
    __half2 h = __builtin_bit_cast(__half2, u);
    return __half22float2(h);
}
__device__ __forceinline__ unsigned f2h2(float a, float b) {
    return __builtin_bit_cast(unsigned, __floats2half2_rn(a, b));
}
// native packed-half LDS atomic add (gfx950 ds_pk_add_f16), fire-and-forget.
// __syncthreads() drains lgkmcnt(0), guaranteeing completion before epilogue.
__device__ __forceinline__ void pk_add_lds(unsigned* p, unsigned v) {
    asm volatile("ds_pk_add_f16 %0, %1"
                 :: "v"((unsigned)(size_t)p), "v"(v) : "memory");
}

// ========== k_count: per-(bin,tile) counts -> global matrix ==========
__global__ void k_count(const int* __restrict__ src, const int* __restrict__ dst,
                        int* __restrict__ cntmat, int E, int halfN, int tiles) {
    __shared__ int cnt[NBIN];
    int t0 = blockIdx.x * TILE;
    for (int l = threadIdx.x; l < NBIN; l += NT) cnt[l] = 0;
    __syncthreads();
    for (int k = 0; k < TILE / (NT * 4); ++k) {
        int idx = t0 + (k * NT + threadIdx.x) * 4;
        if (idx + 3 < E) {
            int4 d4 = ldnt4(dst + idx);
            int4 s4 = ldnt4(src + idx);
            atomicAdd(&cnt[((d4.x >> B2) << 1) | (s4.x >= halfN)], 1);
            atomicAdd(&cnt[((d4.y >> B2) << 1) | (s4.y >= halfN)], 1);
            atomicAdd(&cnt[((d4.z >> B2) << 1) | (s4.z >= halfN)], 1);
            atomicAdd(&cnt[((d4.w >> B2) << 1) | (s4.w >= halfN)], 1);
        } else {
            for (int j = 0; j < 4; ++j)
                if (idx + j < E) {
                    int s = src[idx + j], d = dst[idx + j];
                    atomicAdd(&cnt[((d >> B2) << 1) | (s >= halfN)], 1);
                }
        }
    }
    __syncthreads();
    for (int l = threadIdx.x; l < NBIN; l += NT)
        cntmat[l * tiles + blockIdx.x] = cnt[l];
}

// ===== k_scanA: per-bin exclusive prefix across tiles (in place) + totals =====
__global__ void __launch_bounds__(256)
k_scanA(int* __restrict__ cntmat, int* __restrict__ ghist, int tiles) {
    __shared__ int lds[256];
    int bin = blockIdx.x;
    int* row = cntmat + (size_t)bin * tiles;
    int tid = threadIdx.x;
    int carry = 0;
    for (int base = 0; base < tiles; base += 256) {
        int i = base + tid;
        int v = (i < tiles) ? row[i] : 0;
        lds[tid] = v;
        __syncthreads();
        for (int off = 1; off < 256; off <<= 1) {
            int t = (tid >= off) ? lds[tid - off] : 0;
            __syncthreads();
            lds[tid] += t;
            __syncthreads();
        }
        int incl = lds[tid];
        int tot = lds[255];
        if (i < tiles) row[i] = carry + incl - v;   // exclusive prefix
        carry += tot;
        __syncthreads();
    }
    if (tid == 0) ghist[bin] = carry;
}

// ===== k_scanB: padded (x4) exclusive scan over bin totals -> gbase =====
__global__ void k_scanB(const int* __restrict__ ghist, int* __restrict__ gbase) {
    __shared__ int part[NBIN];
    int tid = threadIdx.x;
    int t = ghist[tid];
    int p = (t + 3) & ~3;                  // padded size
    part[tid] = p;
    __syncthreads();
    for (int off = 1; off < NBIN; off <<= 1) {
        int v = (tid >= off) ? part[tid - off] : 0;
        __syncthreads();
        part[tid] += v;
        __syncthreads();
    }
    gbase[tid] = part[tid] - p;
    if (tid == NBIN - 1) gbase[NBIN] = part[NBIN - 1];
}

// ===== fill pad gaps with sentinels (disjoint from k_place's writes) =====
__global__ void k_pad(const int* __restrict__ ghist, const int* __restrict__ gbase,
                      int* __restrict__ pairs) {
    int b = threadIdx.x;
    int e = gbase[b] + ghist[b];
    int nxt = gbase[b + 1];
    for (; e < nxt; ++e) pairs[e] = SENT;
}

// ====== k_place: deterministic chunk bases from matrix; 1 LDS atomic/edge =====
// copy-out via lbins u16 side-array (bin recorded at placement) -- no search.
__global__ void __launch_bounds__(512)
k_place(const int* __restrict__ src, const int* __restrict__ dst,
        const int* __restrict__ cntmat, const int* __restrict__ ghist,
        const int* __restrict__ gbase, int* __restrict__ pairs,
        int E, int halfN, int tiles) {
    __shared__ int cur[NBIN], gposc[NBIN];
    __shared__ int lbase2[NBIN];
    __shared__ int part[512];
    __shared__ int lbuf[TILE];
    __shared__ unsigned short lbins[TILE];
    __shared__ int totalSh;
    int tile = blockIdx.x;
    int t0 = tile * TILE;
    int tid = threadIdx.x;
    int bA = 2 * tid, bB = 2 * tid + 1;
    int p00 = cntmat[(size_t)bA * tiles + tile];
    int p01 = (tile + 1 < tiles) ? cntmat[(size_t)bA * tiles + tile + 1] : ghist[bA];
    int p10 = cntmat[(size_t)bB * tiles + tile];
    int p11 = (tile + 1 < tiles) ? cntmat[(size_t)bB * tiles + tile + 1] : ghist[bB];
    int c0 = p01 - p00, c1 = p11 - p10;
    gposc[bA] = gbase[bA] + p00;
    gposc[bB] = gbase[bB] + p10;
    int t = c0 + c1;
    part[tid] = t;
    __syncthreads();
    for (int off = 1; off < 512; off <<= 1) {
        int v = (tid >= off) ? part[tid - off] : 0;
        __syncthreads();
        part[tid] += v;
        __syncthreads();
    }
    int ex = part[tid] - t;
    lbase2[bA] = ex;      cur[bA] = ex;
    lbase2[bB] = ex + c0; cur[bB] = ex + c0;
    if (tid == 511) totalSh = part[511];
    __syncthreads();
    // place into LDS sorted by bin; record bin per slot
    for (int k = 0; k < TILE / (512 * 4); ++k) {
        int idx = t0 + (k * 512 + tid) * 4;
        if (idx + 3 < E) {
            int4 s4 = ldnt4(src + idx);
            int4 d4 = ldnt4(dst + idx);
            int b, sl;
            b = ((d4.x >> B2) << 1) | (s4.x >= halfN); sl = atomicAdd(&cur[b], 1);
            lbuf[sl] = s4.x | ((d4.x & (BN - 1)) << 20); lbins[sl] = (unsigned short)b;
            b = ((d4.y >> B2) << 1) | (s4.y >= halfN); sl = atomicAdd(&cur[b], 1);
            lbuf[sl] = s4.y | ((d4.y & (BN - 1)) << 20); lbins[sl] = (unsigned short)b;
            b = ((d4.z >> B2) << 1) | (s4.z >= halfN); sl = atomicAdd(&cur[b], 1);
            lbuf[sl] = s4.z | ((d4.z & (BN - 1)) << 20); lbins[sl] = (unsigned short)b;
            b = ((d4.w >> B2) << 1) | (s4.w >= halfN); sl = atomicAdd(&cur[b], 1);
            lbuf[sl] = s4.w | ((d4.w & (BN - 1)) << 20); lbins[sl] = (unsigned short)b;
        } else {
            for (int j = 0; j < 4; ++j) {
                if (idx + j < E) {
                    int s = src[idx + j], d = dst[idx + j];
                    int b = ((d >> B2) << 1) | (s >= halfN);
                    int sl = atomicAdd(&cur[b], 1);
                    lbuf[sl] = s | ((d & (BN - 1)) << 20);
                    lbins[sl] = (unsigned short)b;
                }
            }
        }
    }
    __syncthreads();
    // coalesced copy-out: direct bin lookup (no binary search)
    int total = totalSh;
    for (int idx = tid; idx < total; idx += 512) {
        int b = lbins[idx];
        pairs[gposc[b] + (idx - lbase2[b])] = lbuf[idx];
    }
}

// ========== per-bucket prep: deg (LDS count) -> dinv, y16 = half2(x*dinv) =====
__global__ void __launch_bounds__(AT)
k_prep(const int* __restrict__ pairs, const int* __restrict__ gbase,
       const float2* __restrict__ x,
       float* __restrict__ dinv, unsigned* __restrict__ y16, int N) {
    __shared__ int cnt[BN];
    int b = blockIdx.x, tid = threadIdx.x;
    int eBeg = gbase[2 * b], eEnd = gbase[2 * b + 2];
    for (int l = tid; l < BN; l += AT) cnt[l] = 0;
    __syncthreads();
    for (int idx = eBeg + (tid << 2); idx < eEnd; idx += AT * 4) {
        int4 v4 = ldnt4(pairs + idx);
        atomicAdd(&cnt[(((unsigned)v4.x) >> 20) & (BN - 1)], (v4.x >= 0) ? 1 : 0);
        atomicAdd(&cnt[(((unsigned)v4.y) >> 20) & (BN - 1)], (v4.y >= 0) ? 1 : 0);
        atomicAdd(&cnt[(((unsigned)v4.z) >> 20) & (BN - 1)], (v4.z >= 0) ? 1 : 0);
        atomicAdd(&cnt[(((unsigned)v4.w) >> 20) & (BN - 1)], (v4.w >= 0) ? 1 : 0);
    }
    __syncthreads();
    int base = b << B2;
    for (int j = tid; j < BN; j += AT) {
        int i = base + j;
        if (i < N) {
            float di = rsqrtf((float)(cnt[j] + 1));
            dinv[i] = di;
            float2 xi = ldnt2f((const float*)(x + i));
            y16[i] = f2h2(xi.x * di, xi.y * di);
        }
    }
}

// ========== layer1 agg: ONE ds_pk_add_f16 per edge (raw half2 bits) ==========
__global__ void __launch_bounds__(AT)
k_bagg1(const int* __restrict__ pairs, const int* __restrict__ gbase,
        const unsigned* __restrict__ y16, const float2* __restrict__ x,
        const float* __restrict__ dinv,
        const float* __restrict__ W1, const float* __restrict__ b1,
        const float* __restrict__ W2,
        float2* __restrict__ partA, float* __restrict__ partB,
        uint2* __restrict__ hfull, int N) {
    __shared__ unsigned accH[BN];
    int b = blockIdx.x, tid = threadIdx.x;
    int eBeg = gbase[2 * b], eEnd = gbase[2 * b + 2];
    for (int l = tid; l < BN; l += AT) accH[l] = 0u;
    __syncthreads();
    for (int idx = eBeg + (tid << 3); idx < eEnd; idx += AT * 8) {
        int4 a = ldnt4(pairs + idx);
        int idx2 = idx + 4;
        int4 bb;
        if (idx2 < eEnd) bb = ldnt4(pairs + idx2);
        else { bb.x = SENT; bb.y = SENT; bb.z = SENT; bb.w = SENT; }
        int sv[8] = {a.x, a.y, a.z, a.w, bb.x, bb.y, bb.z, bb.w};
        unsigned rv[8];
        #pragma unroll
        for (int q = 0; q < 8; ++q)
            rv[q] = y16[sv[q] & 0xFFFFF];
        #pragma unroll
        for (int q = 0; q < 8; ++q) {
            unsigned data = (sv[q] >= 0) ? rv[q] : 0u;
            int dl = (((unsigned)sv[q]) >> 20) & (BN - 1);
            pk_add_lds(&accH[dl], data);
        }
    }
    __syncthreads();
    int base = b << B2;
    for (int j = tid; j < BN; j += AT) {
        int i = base + j;
        if (i >= N) continue;
        float2 a = h2f2(accH[j]);
        float di = dinv[i];
        float2 xi = ldnt2f((const float*)(x + i));
        float ay0 = a.x + xi.x * di;       // self loop fp32
        float ay1 = a.y + xi.y * di;
        float o0 = fmaxf(di * (ay0 * W1[0] + ay1 * W1[4]) + b1[0], 0.f);
        float o1 = fmaxf(di * (ay0 * W1[1] + ay1 * W1[5]) + b1[1], 0.f);
        float o2 = fmaxf(di * (ay0 * W1[2] + ay1 * W1[6]) + b1[2], 0.f);
        float o3 = fmaxf(di * (ay0 * W1[3] + ay1 * W1[7]) + b1[3], 0.f);
        float h0 = (o0 * W2[0] + o1 * W2[3] + o2 * W2[6] + o3 * W2[9])  * di;
        float h1 = (o0 * W2[1] + o1 * W2[4] + o2 * W2[7] + o3 * W2[10]) * di;
        float hv2 = (o0 * W2[2] + o1 * W2[5] + o2 * W2[8] + o3 * W2[11]) * di;
        // self-loop running sums (fp32) for layer 2
        v2f sA; sA.x = h0; sA.y = h1;
        __builtin_nontemporal_store(sA, (v2f*)(partA + i));
        __builtin_nontemporal_store(hv2, partB + i);
        // packed half4 gather record: ONE 8B load per edge in layer 2
        uint2 hp; hp.x = f2h2(h0, h1); hp.y = f2h2(hv2, 0.f);
        hfull[i] = hp;
    }
}

// ===== layer2 phase LO: src < halfN edges, 4MB L2-resident gather region =====
__global__ void __launch_bounds__(AT)
k_bagg2lo(const int* __restrict__ pairs, const int* __restrict__ gbase,
          const uint2* __restrict__ hfull,
          float2* __restrict__ partA, float* __restrict__ partB, int N) {
    __shared__ unsigned acc01[BN];
    __shared__ float acc2[BN];
    int b = blockIdx.x, tid = threadIdx.x;
    int eBeg = gbase[2 * b], eEnd = gbase[2 * b + 1];
    for (int l = tid; l < BN; l += AT) { acc01[l] = 0u; acc2[l] = 0.f; }
    __syncthreads();
    for (int idx = eBeg + (tid << 3); idx < eEnd; idx += AT * 8) {
        int4 a = ldnt4(pairs + idx);
        int idx2 = idx + 4;
        int4 bb;
        if (idx2 < eEnd) bb = ldnt4(pairs + idx2);
        else { bb.x = SENT; bb.y = SENT; bb.z = SENT; bb.w = SENT; }
        int sv[8] = {a.x, a.y, a.z, a.w, bb.x, bb.y, bb.z, bb.w};
        uint2 r[8];
        #pragma unroll
        for (int q = 0; q < 8; ++q)
            r[q] = hfull[sv[q] & 0xFFFFF];
        #pragma unroll
        for (int q = 0; q < 8; ++q) {
            int dl = (((unsigned)sv[q]) >> 20) & (BN - 1);
            unsigned d01 = (sv[q] >= 0) ? r[q].x : 0u;
            float    f2v = (sv[q] >= 0) ? h2f2(r[q].y).x : 0.f;
            pk_add_lds(&acc01[dl], d01);
            atomicAdd(&acc2[dl], f2v);
        }
    }
    __syncthreads();
    int base = b << B2;
    for (int j = tid; j < BN; j += AT) {
        int i = base + j;
        if (i >= N) continue;
        float2 a01 = h2f2(acc01[j]);
        float2 pa = ldnt2f((const float*)(partA + i));
        float pb = __builtin_nontemporal_load(partB + i);
        v2f oA; oA.x = pa.x + a01.x; oA.y = pa.y + a01.y;
        __builtin_nontemporal_store(oA, (v2f*)(partA + i));
        __builtin_nontemporal_store(pb + acc2[j], partB + i);
    }
}

// ===== layer2 phase HI: src >= halfN edges + sigmoid + MLP epilogue =====
__global__ void __launch_bounds__(AT)
k_bagg2hi(const int* __restrict__ pairs, const int* __restrict__ gbase,
          const uint2* __restrict__ hfull,
          const float2* __restrict__ partA, const float* __restrict__ partB,
          const float* __restrict__ dinv,
          const float* __restrict__ b2,
          const float* __restrict__ W3, const float* __restrict__ b3,
          const float* __restrict__ W4, const float* __restrict__ b4,
          const float* __restrict__ W5, const float* __restrict__ b5,
          float* __restrict__ out, int N) {
    __shared__ unsigned acc01[BN];
    __shared__ float acc2[BN];
    int b = blockIdx.x, tid = threadIdx.x;
    int eBeg = gbase[2 * b + 1], eEnd = gbase[2 * b + 2];
    for (int l = tid; l < BN; l += AT) { acc01[l] = 0u; acc2[l] = 0.f; }
    __syncthreads();
    for (int idx = eBeg + (tid << 3); idx < eEnd; idx += AT * 8) {
        int4 a = ldnt4(pairs + idx);
        int idx2 = idx + 4;
        int4 bb;
        if (idx2 < eEnd) bb = ldnt4(pairs + idx2);
        else { bb.x = SENT; bb.y = SENT; bb.z = SENT; bb.w = SENT; }
        int sv[8] = {a.x, a.y, a.z, a.w, bb.x, bb.y, bb.z, bb.w};
        uint2 r[8];
        #pragma unroll
        for (int q = 0; q < 8; ++q)
            r[q] = hfull[sv[q] & 0xFFFFF];
        #pragma unroll
        for (int q = 0; q < 8; ++q) {
            int dl = (((unsigned)sv[q]) >> 20) & (BN - 1);
            unsigned d01 = (sv[q] >= 0) ? r[q].x : 0u;
            float    f2v = (sv[q] >= 0) ? h2f2(r[q].y).x : 0.f;
            pk_add_lds(&acc01[dl], d01);
            atomicAdd(&acc2[dl], f2v);
        }
    }
    __syncthreads();
    int base = b << B2;
    for (int j = tid; j < BN; j += AT) {
        int i = base + j;
        if (i >= N) continue;
        float2 a01 = h2f2(acc01[j]);
        float2 pa = ldnt2f((const float*)(partA + i));
        float pb = __builtin_nontemporal_load(partB + i);
        float s0 = pa.x + a01.x;
        float s1 = pa.y + a01.y;
        float s2 = pb + acc2[j];
        float di = __builtin_nontemporal_load(dinv + i);
        float z0 = di * s0 + b2[0];
        float z1 = di * s1 + b2[1];
        float z2 = di * s2 + b2[2];
        float g0 = 1.f / (1.f + expf(-z0));
        float g1 = 1.f / (1.f + expf(-z1));
        float g2 = 1.f / (1.f + expf(-z2));
        float t0 = fmaxf(g0 * W3[0] + g1 * W3[4] + g2 * W3[8]  + b3[0], 0.f);
        float t1 = fmaxf(g0 * W3[1] + g1 * W3[5] + g2 * W3[9]  + b3[1], 0.f);
        float t2 = fmaxf(g0 * W3[2] + g1 * W3[6] + g2 * W3[10] + b3[2], 0.f);
        float t3 = fmaxf(g0 * W3[3] + g1 * W3[7] + g2 * W3[11] + b3[3], 0.f);
        float u0 = fmaxf(t0 * W4[0] + t1 * W4[3] + t2 * W4[6] + t3 * W4[9]  + b4[0], 0.f);
        float u1 = fmaxf(t0 * W4[1] + t1 * W4[4] + t2 * W4[7] + t3 * W4[10] + b4[1], 0.f);
        float u2 = fmaxf(t0 * W4[2] + t1 * W4[5] + t2 * W4[8] + t3 * W4[11] + b4[2], 0.f);
        out[i] = u0 * W5[0] + u1 * W5[1] + u2 * W5[2] + b5[0];
    }
}

// ================= fallback path (round-2 global CSR, fp32) =================
__global__ void k_deg(const int* __restrict__ dst, int* __restrict__ deg, int E) {
    int e = blockIdx.x * blockDim.x + threadIdx.x;
    if (e < E) atomicAdd(deg + dst[e], 1);
}
__global__ void k_scan1(const int* __restrict__ deg, int* __restrict__ row,
                        int* __restrict__ bsum, int N) {
    __shared__ int lds[NT];
    int base = blockIdx.x * SCAN_E + threadIdx.x * 4;
    int d0 = 0, d1 = 0, d2 = 0, d3 = 0;
    if (base + 3 < N) {
        int4 v = *(const int4*)(deg + base);
        d0 = v.x; d1 = v.y; d2 = v.z; d3 = v.w;
    } else {
        if (base     < N) d0 = deg[base];
        if (base + 1 < N) d1 = deg[base + 1];
        if (base + 2 < N) d2 = deg[base + 2];
        if (base + 3 < N) d3 = deg[base + 3];
    }
    int t = d0 + d1 + d2 + d3;
    lds[threadIdx.x] = t;
    __syncthreads();
    for (int off = 1; off < NT; off <<= 1) {
        int v = (threadIdx.x >= off) ? lds[threadIdx.x - off] : 0;
        __syncthreads();
        lds[threadIdx.x] += v;
        __syncthreads();
    }
    int excl = lds[threadIdx.x] - t;
    if (threadIdx.x == NT - 1) bsum[blockIdx.x] = lds[NT - 1];
    if (base     < N) row[base]     = excl;
    if (base + 1 < N) row[base + 1] = excl + d0;
    if (base + 2 < N) row[base + 2] = excl + d0 + d1;
    if (base + 3 < N) row[base + 3] = excl + d0 + d1 + d2;
}
__global__ void k_scan2(int* __restrict__ bsum, int M) {
    __shared__ int lds[NT];
    int base = threadIdx.x * 4;
    int d0 = 0, d1 = 0, d2 = 0, d3 = 0;
    if (base     < M) d0 = bsum[base];
    if (base + 1 < M) d1 = bsum[base + 1];
    if (base + 2 < M) d2 = bsum[base + 2];
    if (base + 3 < M) d3 = bsum[base + 3];
    int t = d0 + d1 + d2 + d3;
    lds[threadIdx.x] = t;
    __syncthreads();
    for (int off = 1; off < NT; off <<= 1) {
        int v = (threadIdx.x >= off) ? lds[threadIdx.x - off] : 0;
        __syncthreads();
        lds[threadIdx.x] += v;
        __syncthreads();
    }
    int excl = lds[threadIdx.x] - t;
    if (base     < M) bsum[base]     = excl;
    if (base + 1 < M) bsum[base + 1] = excl + d0;
    if (base + 2 < M) bsum[base + 2] = excl + d0 + d1;
    if (base + 3 < M) bsum[base + 3] = excl + d0 + d1 + d2;
}
__global__ void k_scan3(int* __restrict__ row, const int* __restrict__ bsum, int N) {
    int base = blockIdx.x * SCAN_E + threadIdx.x * 4;
    int add = bsum[blockIdx.x];
    if (base + 3 < N) {
        int4 v = *(int4*)(row + base);
        v.x += add; v.y += add; v.z += add; v.w += add;
        *(int4*)(row + base) = v;
    } else {
        if (base     < N) row[base]     += add;
        if (base + 1 < N) row[base + 1] += add;
        if (base + 2 < N) row[base + 2] += add;
    }
}
__global__ void k_scatter(const int* __restrict__ src, const int* __restrict__ dst,
                          int* __restrict__ row, int* __restrict__ ss, int E) {
    int e = blockIdx.x * blockDim.x + threadIdx.x;
    if (e >= E) return;
    int s = src[e], d = dst[e];
    int slot = atomicAdd(row + d, 1);
    ss[slot] = s;
}
__global__ void k_node1_fb(const float2* __restrict__ x, const int* __restrict__ deg,
                           const float* __restrict__ W1,
                           float* __restrict__ dinv, float4* __restrict__ hp, int N) {
    int i = blockIdx.x * blockDim.x + threadIdx.x;
    if (i >= N) return;
    float2 xi = x[i];
    float di = rsqrtf((float)(deg[i] + 1));
    dinv[i] = di;
    float4 h;
    h.x = (xi.x * W1[0] + xi.y * W1[4]) * di;
    h.y = (xi.x * W1[1] + xi.y * W1[5]) * di;
    h.z = (xi.x * W1[2] + xi.y * W1[6]) * di;
    h.w = (xi.x * W1[3] + xi.y * W1[7]) * di;
    hp[i] = h;
}
__global__ void k_aggf1_fb(const int* __restrict__ row, const int* __restrict__ ss,
                           const float4* __restrict__ hp1, const float* __restrict__ dinv,
                           const float* __restrict__ b1, const float* __restrict__ W2,
                           float4* __restrict__ hp2, int N) {
    int i = blockIdx.x * blockDim.x + threadIdx.x;
    if (i >= N) return;
    int beg = (i == 0) ? 0 : row[i - 1];
    int end = row[i];
    float4 a = hp1[i];
    for (int e = beg; e < end; ++e) {
        float4 ha = hp1[ss[e]];
        a.x += ha.x; a.y += ha.y; a.z += ha.z; a.w += ha.w;
    }
    float di = dinv[i];
    float o0 = fmaxf(di * a.x + b1[0], 0.f);
    float o1 = fmaxf(di * a.y + b1[1], 0.f);
    float o2 = fmaxf(di * a.z + b1[2], 0.f);
    float o3 = fmaxf(di * a.w + b1[3], 0.f);
    float4 h;
    h.x = (o0 * W2[0] + o1 * W2[3] + o2 * W2[6] + o3 * W2[9])  * di;
    h.y = (o0 * W2[1] + o1 * W2[4] + o2 * W2[7] + o3 * W2[10]) * di;
    h.z = (o0 * W2[2] + o1 * W2[5] + o2 * W2[8] + o3 * W2[11]) * di;
    h.w = 0.f;
    hp2[i] = h;
}
__global__ void k_aggf2_fb(const int* __restrict__ row, const int* __restrict__ ss,
                           const float4* __restrict__ hp2, const float* __restrict__ dinv,
                           const float* __restrict__ b2,
                           const float* __restrict__ W3, const float* __restrict__ b3,
                           const float* __restrict__ W4, const float* __restrict__ b4,
                           const float* __restrict__ W5, const float* __restrict__ b5,
                           float* __restrict__ out, int N) {
    int i = blockIdx.x * blockDim.x + threadIdx.x;
    if (i >= N) return;
    int beg = (i == 0) ? 0 : row[i - 1];
    int end = row[i];
    float4 a = hp2[i];
    for (int e = beg; e < end; ++e) {
        float4 ha = hp2[ss[e]];
        a.x += ha.x; a.y += ha.y; a.z += ha.z;
    }
    float di = dinv[i];
    float z0 = di * a.x + b2[0];
    float z1 = di * a.y + b2[1];
    float z2 = di * a.z + b2[2];
    float g0 = 1.f / (1.f + expf(-z0));
    float g1 = 1.f / (1.f + expf(-z1));
    float g2 = 1.f / (1.f + expf(-z2));
    float t0 = fmaxf(g0 * W3[0] + g1 * W3[4] + g2 * W3[8]  + b3[0], 0.f);
    float t1 = fmaxf(g0 * W3[1] + g1 * W3[5] + g2 * W3[9]  + b3[1], 0.f);
    float t2 = fmaxf(g0 * W3[2] + g1 * W3[6] + g2 * W3[10] + b3[2], 0.f);
    float t3 = fmaxf(g0 * W3[3] + g1 * W3[7] + g2 * W3[11] + b3[3], 0.f);
    float u0 = fmaxf(t0 * W4[0] + t1 * W4[3] + t2 * W4[6] + t3 * W4[9]  + b4[0], 0.f);
    float u1 = fmaxf(t0 * W4[1] + t1 * W4[4] + t2 * W4[7] + t3 * W4[10] + b4[1], 0.f);
    float u2 = fmaxf(t0 * W4[2] + t1 * W4[5] + t2 * W4[8] + t3 * W4[11] + b4[2], 0.f);
    out[i] = u0 * W5[0] + u1 * W5[1] + u2 * W5[2] + b5[0];
}

extern "C" void kernel_launch(void* const* d_in, const int* in_sizes, int n_in,
                              void* d_out, int out_size, void* d_ws, size_t ws_size,
                              hipStream_t stream) {
    const float* x  = (const float*)d_in[0];
    const int*   ei = (const int*)d_in[1];
    const float* W1 = (const float*)d_in[2];
    const float* b1 = (const float*)d_in[3];
    const float* W2 = (const float*)d_in[4];
    const float* b2 = (const float*)d_in[5];
    const float* W3 = (const float*)d_in[6];
    const float* b3 = (const float*)d_in[7];
    const float* W4 = (const float*)d_in[8];
    const float* b4 = (const float*)d_in[9];
    const float* W5 = (const float*)d_in[10];
    const float* b5 = (const float*)d_in[11];

    const int N = in_sizes[0] / 2;
    const int E = in_sizes[1] / 2;
    const int* src = ei;
    const int* dst = ei + E;

    const int gbN = (N + NT - 1) / NT;
    const int gbE = (E + NT - 1) / NT;
    const int tiles = (E + TILE - 1) / TILE;
    const int NB = (N + BN - 1) >> B2;
    const int halfN = (N + 1) >> 1;

    char* ws = (char*)d_ws;

    // -------- primary: matrix-scan sort (count once) + per-bucket LDS agg ----
    size_t szPairs  = (size_t)(E + 4 * NBIN) * 4;
    size_t offPartA = (szPairs + 15) & ~(size_t)15;
    size_t offPartB = offPartA + (size_t)N * 8;
    size_t offY16   = offPartB + (size_t)N * 4;
    size_t offDinv  = offY16 + (size_t)N * 4;
    size_t offHfull = offDinv + (size_t)N * 4;
    size_t offCnt   = (offHfull + (size_t)N * 8 + 15) & ~(size_t)15;
    size_t offHist  = (offCnt + (size_t)NBIN * tiles * 4 + 15) & ~(size_t)15;
    size_t need1    = offHist + (size_t)(2 * NBIN + 2) * 4 + 64;

    if (N <= (1 << 20) && NB <= NBMAX && ws_size >= need1) {
        int*      pairs  = (int*)ws;
        float2*   partA  = (float2*)(ws + offPartA);
        float*    partB  = (float*)(ws + offPartB);
        unsigned* y16    = (unsigned*)(ws + offY16);
        float*    dinv   = (float*)(ws + offDinv);
        uint2*    hfull  = (uint2*)(ws + offHfull);
        int*      cntmat = (int*)(ws + offCnt);
        int*      ghist  = (int*)(ws + offHist);
        int*      gbase  = ghist + NBIN;

        k_count  <<<tiles, NT, 0, stream>>>(src, dst, cntmat, E, halfN, tiles);
        k_scanA  <<<NBIN, 256, 0, stream>>>(cntmat, ghist, tiles);
        k_scanB  <<<1, NBIN, 0, stream>>>(ghist, gbase);
        k_pad    <<<1, NBIN, 0, stream>>>(ghist, gbase, pairs);
        k_place  <<<tiles, 512, 0, stream>>>(src, dst, cntmat, ghist, gbase,
                                             pairs, E, halfN, tiles);
        k_prep   <<<NB, AT, 0, stream>>>(pairs, gbase, (const float2*)x,
                                         dinv, y16, N);
        k_bagg1  <<<NB, AT, 0, stream>>>(pairs, gbase, y16, (const float2*)x,
                                         dinv, W1, b1, W2, partA, partB,
                                         hfull, N);
        k_bagg2lo<<<NB, AT, 0, stream>>>(pairs, gbase, hfull, partA, partB, N);
        k_bagg2hi<<<NB, AT, 0, stream>>>(pairs, gbase, hfull, partA, partB,
                                         dinv, b2, W3, b3, W4, b4, W5, b5,
                                         (float*)d_out, N);
        return;
    }

    // -------- fallback: global counting-sort CSR (fp32) --------
    const int nScanBlocks = (N + SCAN_E - 1) / SCAN_E;
    size_t need2 = (size_t)N * 44 + (size_t)E * 4 + (size_t)nScanBlocks * 4 + 256;
    if (ws_size >= need2 && nScanBlocks <= NT * 4) {
        float4* hp1  = (float4*)ws;
        float4* hp2  = (float4*)(ws + (size_t)N * 16);
        int*    ss   = (int*)   (ws + (size_t)N * 32);
        int*    deg  = (int*)   (ws + (size_t)N * 32 + (size_t)E * 4);
        int*    row  = (int*)   (ws + (size_t)N * 36 + (size_t)E * 4);
        float*  dinv = (float*) (ws + (size_t)N * 40 + (size_t)E * 4);
        int*    bsum = (int*)   (ws + (size_t)N * 44 + (size_t)E * 4);

        hipMemsetAsync(deg, 0, (size_t)N * 4, stream);
        k_deg     <<<gbE, NT, 0, stream>>>(dst, deg, E);
        k_scan1   <<<nScanBlocks, NT, 0, stream>>>(deg, row, bsum, N);
        k_scan2   <<<1, NT, 0, stream>>>(bsum, nScanBlocks);
        k_scan3   <<<nScanBlocks, NT, 0, stream>>>(row, bsum, N);
        k_node1_fb<<<gbN, NT, 0, stream>>>((const float2*)x, deg, W1, dinv, hp1, N);
        k_scatter <<<gbE, NT, 0, stream>>>(src, dst, row, ss, E);
        k_aggf1_fb<<<gbN, NT, 0, stream>>>(row, ss, hp1, dinv, b1, W2, hp2, N);
        k_aggf2_fb<<<gbN, NT, 0, stream>>>(row, ss, hp2, dinv, b2, W3, b3, W4, b4,
                                           W5, b5, (float*)d_out, N);
    }
}